// Round 1
// baseline (4428.228 us; speedup 1.0000x reference)
//
#include <hip/hip_runtime.h>
#include <math.h>

// Problem constants
#define B_    16384
#define N_    1152
#define S_    576
#define F_    8
#define KTOT  2352   // 1152 + 576 + 576 + 24 + 24
#define NOUT  4608   // S_*F_  (n = s*8 + f)
#define CVROW 1200   // 576+576+24+24
#define NTILE 36     // NOUT/128

#define LOG2F_ 0.69314718055994530942f

__device__ __forceinline__ float log_cosh_f(float t) {
    float a = fabsf(t);
    // |x| + log1p(exp(-2|x|)) - log(2); exp underflows to 0 for large a -> a - log2
    return a + __logf(1.0f + __expf(-2.0f * a)) - LOG2F_;
}

// ---------------------------------------------------------------------------
// Kernel 1: gather weights.
//   W[k][n]  for k in [0,2352), n = s*8+f       (theta weights)
//   LW[j2][c][n] for j2 in {0,1}, c in [0,24)   (loop-correlator weights)
// One thread per (kslot, s); kslot in [0,2400): 0..2351 -> W, 2352..2399 -> LW.
// ---------------------------------------------------------------------------
__global__ __launch_bounds__(256) void build_w(
    const int* __restrict__ symm,
    const int* __restrict__ c0s, const int* __restrict__ c1s,
    const int* __restrict__ c2s, const int* __restrict__ c3s,
    const float* __restrict__ sk,
    const float* __restrict__ ck0, const float* __restrict__ ck1,
    const float* __restrict__ ck2, const float* __restrict__ ck3,
    const float* __restrict__ l0k, const float* __restrict__ l1k,
    float* __restrict__ W, float* __restrict__ LW)
{
    int flat = blockIdx.x * 256 + threadIdx.x;   // kslot*576 + s, grid exact
    int kslot = flat / 576;
    int s = flat - kslot * 576;

    int m, stride;
    const float* tab;
    float* dst;
    if (kslot < 1152) {
        m = symm[s * N_ + kslot]; tab = sk; stride = N_;
        dst = W + (size_t)kslot * NOUT + s * 8;
    } else if (kslot < 1728) {
        int c = kslot - 1152; m = c0s[s * 576 + c]; tab = ck0; stride = 576;
        dst = W + (size_t)kslot * NOUT + s * 8;
    } else if (kslot < 2304) {
        int c = kslot - 1728; m = c1s[s * 576 + c]; tab = ck1; stride = 576;
        dst = W + (size_t)kslot * NOUT + s * 8;
    } else if (kslot < 2328) {
        int c = kslot - 2304; m = c2s[s * 24 + c]; tab = ck2; stride = 24;
        dst = W + (size_t)kslot * NOUT + s * 8;
    } else if (kslot < 2352) {
        int c = kslot - 2328; m = c3s[s * 24 + c]; tab = ck3; stride = 24;
        dst = W + (size_t)kslot * NOUT + s * 8;
    } else if (kslot < 2376) {
        int c = kslot - 2352; m = c2s[s * 24 + c]; tab = l0k; stride = 24;
        dst = LW + (size_t)c * NOUT + s * 8;
    } else {
        int c = kslot - 2376; m = c3s[s * 24 + c]; tab = l1k; stride = 24;
        dst = LW + (size_t)(24 + c) * NOUT + s * 8;
    }
#pragma unroll
    for (int f = 0; f < 8; ++f) dst[f] = tab[f * stride + m];
}

// ---------------------------------------------------------------------------
// Kernel 2: per-sample correlator values (fp32 exact) + scalar bias init.
// One block (256 thr) per b. CV row: [0,576) cv0 | [576,1152) cv1 |
// [1152,1176) cv2 | [1176,1200) cv3.  initb[b] = visible-bias + sum cb_i*sum(cv_i)
// ---------------------------------------------------------------------------
__global__ __launch_bounds__(256) void build_cv(
    const float* __restrict__ x,
    const int* __restrict__ corr0, const int* __restrict__ corr1,
    const int* __restrict__ corr2, const int* __restrict__ corr3,
    const float* __restrict__ vb,
    const float* __restrict__ cb0, const float* __restrict__ cb1,
    const float* __restrict__ cb2, const float* __restrict__ cb3,
    float* __restrict__ CV, float* __restrict__ initb)
{
    __shared__ float xs[N_];
    __shared__ float red[256];
    const int tid = threadIdx.x;
    const int b = blockIdx.x;
    const float vb0 = vb[0], vb1 = vb[1];

    float bias = 0.f;
    for (int i = tid; i < N_; i += 256) {
        float v = x[(size_t)b * N_ + i];
        xs[i] = v;
        bias += v * ((i & 1) ? vb1 : vb0);
    }
    __syncthreads();

    float s0 = 0.f, s1 = 0.f, s2 = 0.f, s3 = 0.f;
    for (int c = tid; c < 576; c += 256) {
        const int* i0 = corr0 + c * 4;
        float p = xs[i0[0]] * xs[i0[1]] * xs[i0[2]] * xs[i0[3]];
        CV[(size_t)b * CVROW + c] = p; s0 += p;
        const int* i1 = corr1 + c * 4;
        float q = xs[i1[0]] * xs[i1[1]] * xs[i1[2]] * xs[i1[3]];
        CV[(size_t)b * CVROW + 576 + c] = q; s1 += q;
    }
    if (tid < 24) {
        const int* i2 = corr2 + tid * 24;
        float p = 1.f;
        for (int j = 0; j < 24; ++j) p *= xs[i2[j]];
        CV[(size_t)b * CVROW + 1152 + tid] = p; s2 = p;
        const int* i3 = corr3 + tid * 24;
        float q = 1.f;
        for (int j = 0; j < 24; ++j) q *= xs[i3[j]];
        CV[(size_t)b * CVROW + 1176 + tid] = q; s3 = q;
    }
    bias += cb0[0] * s0 + cb1[0] * s1 + cb2[0] * s2 + cb3[0] * s3;

    red[tid] = bias;
    __syncthreads();
    for (int off = 128; off; off >>= 1) {
        if (tid < off) red[tid] += red[tid + off];
        __syncthreads();
    }
    if (tid == 0) initb[b] = red[0];
}

// ---------------------------------------------------------------------------
// Kernel 3: main GEMM + log_cosh epilogue + fused loop-correlator terms.
// C-tile 128x128 (b x n), BK=16, 256 threads, 8x8 per-thread micro-tile.
// Writes per-(n-tile) partial row sums (deterministic, no atomics).
// ---------------------------------------------------------------------------
__global__ __launch_bounds__(256) void main_gemm(
    const float* __restrict__ x, const float* __restrict__ CV,
    const float* __restrict__ W, const float* __restrict__ LW,
    const float* __restrict__ hidden_bias,
    const float* __restrict__ l0hb, const float* __restrict__ l1hb,
    float* __restrict__ partials)
{
    // shared union: mm phase (A[16][132], W[16][132]) | loop phase
    // (cv[2][128][25], LW[2][24][132]) | reduce (red[16][129])
    __shared__ float sh[12736];
    const int tid = threadIdx.x;
    const int tx = tid & 15, ty = tid >> 4;
    const int n0 = blockIdx.x * 128;
    const int b0 = blockIdx.y * 128;

    float* As = sh;              // [16][132] k-major
    float* Wt = sh + 16 * 132;   // [16][132]

    float acc[8][8];
#pragma unroll
    for (int r = 0; r < 8; ++r)
#pragma unroll
        for (int c = 0; c < 8; ++c) acc[r][c] = 0.f;

    for (int kc = 0; kc < KTOT / 16; ++kc) {
        const int kg = kc * 16;
        // stage A tile (128 rows x 16 k), float4 loads, transposed store
#pragma unroll
        for (int i = 0; i < 2; ++i) {
            int f4 = tid + i * 256;           // 512 float4s
            int row = f4 >> 2, kq = f4 & 3;
            int k = kg + kq * 4;              // chunk never straddles x/CV split
            int b = b0 + row;
            float4 v = (k < N_)
                ? *(const float4*)&x[(size_t)b * N_ + k]
                : *(const float4*)&CV[(size_t)b * CVROW + (k - N_)];
            As[(kq * 4 + 0) * 132 + row] = v.x;
            As[(kq * 4 + 1) * 132 + row] = v.y;
            As[(kq * 4 + 2) * 132 + row] = v.z;
            As[(kq * 4 + 3) * 132 + row] = v.w;
        }
        // stage W tile (16 k x 128 n), float4
#pragma unroll
        for (int i = 0; i < 2; ++i) {
            int f4 = tid + i * 256;
            int kk = f4 >> 5, colq = f4 & 31;
            *(float4*)&Wt[kk * 132 + colq * 4] =
                *(const float4*)&W[(size_t)(kg + kk) * NOUT + n0 + colq * 4];
        }
        __syncthreads();
#pragma unroll
        for (int kk = 0; kk < 16; ++kk) {
            const float4 a0 = *(const float4*)&As[kk * 132 + ty * 8];
            const float4 a1 = *(const float4*)&As[kk * 132 + ty * 8 + 4];
            const float4 w0 = *(const float4*)&Wt[kk * 132 + tx * 8];
            const float4 w1 = *(const float4*)&Wt[kk * 132 + tx * 8 + 4];
            const float a[8] = {a0.x, a0.y, a0.z, a0.w, a1.x, a1.y, a1.z, a1.w};
            const float w[8] = {w0.x, w0.y, w0.z, w0.w, w1.x, w1.y, w1.z, w1.w};
#pragma unroll
            for (int r = 0; r < 8; ++r)
#pragma unroll
                for (int c = 0; c < 8; ++c)
                    acc[r][c] = fmaf(a[r], w[c], acc[r][c]);
        }
        __syncthreads();
    }

    // epilogue 1: theta -> log_cosh row sums (f = n % 8 = u)
    float rowsum[8];
#pragma unroll
    for (int r = 0; r < 8; ++r) rowsum[r] = 0.f;
    {
        float hb[8];
#pragma unroll
        for (int u = 0; u < 8; ++u) hb[u] = hidden_bias[u];
#pragma unroll
        for (int r = 0; r < 8; ++r)
#pragma unroll
            for (int u = 0; u < 8; ++u)
                rowsum[r] += log_cosh_f(acc[r][u] + hb[u]);
    }

    // loop-correlator phase: lt[b,n] = sum_c cv{2,3}[b,c] * LW[j2][c][n] + lhb[f]
    float* cvs = sh;                 // [2][128][25] (padded)
    float* LWs = sh + 2 * 128 * 25;  // [2][24][132]
    for (int i = tid; i < 128 * 48; i += 256) {
        int row = i / 48, cc = i - row * 48;
        int j2 = cc / 24, c = cc - j2 * 24;
        cvs[(j2 * 128 + row) * 25 + c] = CV[(size_t)(b0 + row) * CVROW + 1152 + cc];
    }
    for (int i = tid; i < 2 * 24 * 128; i += 256) {
        int j2 = i / 3072, rem = i - j2 * 3072;
        int c = rem >> 7, col = rem & 127;
        LWs[(j2 * 24 + c) * 132 + col] = LW[(size_t)(j2 * 24 + c) * NOUT + n0 + col];
    }
    __syncthreads();
#pragma unroll
    for (int j2 = 0; j2 < 2; ++j2) {
        float acc2[8][8];
#pragma unroll
        for (int r = 0; r < 8; ++r)
#pragma unroll
            for (int c = 0; c < 8; ++c) acc2[r][c] = 0.f;
        for (int c = 0; c < 24; ++c) {
            float a[8];
#pragma unroll
            for (int r = 0; r < 8; ++r)
                a[r] = cvs[(j2 * 128 + ty * 8 + r) * 25 + c];
            const float4 w0 = *(const float4*)&LWs[(j2 * 24 + c) * 132 + tx * 8];
            const float4 w1 = *(const float4*)&LWs[(j2 * 24 + c) * 132 + tx * 8 + 4];
            const float w[8] = {w0.x, w0.y, w0.z, w0.w, w1.x, w1.y, w1.z, w1.w};
#pragma unroll
            for (int r = 0; r < 8; ++r)
#pragma unroll
                for (int u = 0; u < 8; ++u)
                    acc2[r][u] = fmaf(a[r], w[u], acc2[r][u]);
        }
        const float* lhbp = j2 ? l1hb : l0hb;
#pragma unroll
        for (int r = 0; r < 8; ++r)
#pragma unroll
            for (int u = 0; u < 8; ++u)
                rowsum[r] += log_cosh_f(acc2[r][u] + lhbp[u]);
    }

    // cross-thread row reduction (over tx), write per-n-tile partials
    __syncthreads();
    float* red = sh;  // [16][129]
#pragma unroll
    for (int j = 0; j < 8; ++j) red[tx * 129 + ty * 8 + j] = rowsum[j];
    __syncthreads();
    if (tid < 128) {
        float ssum = 0.f;
#pragma unroll
        for (int t2 = 0; t2 < 16; ++t2) ssum += red[t2 * 129 + tid];
        partials[(size_t)blockIdx.x * B_ + b0 + tid] = ssum;
    }
}

// ---------------------------------------------------------------------------
// Kernel 4: out[b] = initb[b] + sum over n-tiles of partials
// ---------------------------------------------------------------------------
__global__ __launch_bounds__(256) void finalize_out(
    const float* __restrict__ initb, const float* __restrict__ partials,
    float* __restrict__ out)
{
    int b = blockIdx.x * 256 + threadIdx.x;
    float s = initb[b];
#pragma unroll
    for (int t = 0; t < NTILE; ++t) s += partials[(size_t)t * B_ + b];
    out[b] = s;
}

extern "C" void kernel_launch(void* const* d_in, const int* in_sizes, int n_in,
                              void* d_out, int out_size, void* d_ws, size_t ws_size,
                              hipStream_t stream) {
    const float* x    = (const float*)d_in[0];
    const int* symm   = (const int*)d_in[1];
    const int* corr0  = (const int*)d_in[2];
    const int* corr1  = (const int*)d_in[3];
    const int* corr2  = (const int*)d_in[4];
    const int* corr3  = (const int*)d_in[5];
    const int* c0s    = (const int*)d_in[6];
    const int* c1s    = (const int*)d_in[7];
    const int* c2s    = (const int*)d_in[8];
    const int* c3s    = (const int*)d_in[9];
    const float* hb   = (const float*)d_in[10];
    const float* sk   = (const float*)d_in[11];
    const float* vb   = (const float*)d_in[12];
    const float* cb0  = (const float*)d_in[13];
    const float* ck0  = (const float*)d_in[14];
    const float* cb1  = (const float*)d_in[15];
    const float* ck1  = (const float*)d_in[16];
    const float* cb2  = (const float*)d_in[17];
    const float* ck2  = (const float*)d_in[18];
    const float* cb3  = (const float*)d_in[19];
    const float* ck3  = (const float*)d_in[20];
    const float* l0hb = (const float*)d_in[21];
    const float* l0k  = (const float*)d_in[22];
    const float* l1hb = (const float*)d_in[23];
    const float* l1k  = (const float*)d_in[24];

    // workspace layout (floats); total = 31,326,208 f = 125.3 MB
    float* ws = (float*)d_ws;
    float* W        = ws;                                  // KTOT*NOUT
    float* LW       = W + (size_t)KTOT * NOUT;             // 48*NOUT
    float* CV       = LW + (size_t)48 * NOUT;              // B_*CVROW
    float* initb    = CV + (size_t)B_ * CVROW;             // B_
    float* partials = initb + B_;                          // NTILE*B_

    build_w<<<(2400 * 576) / 256, 256, 0, stream>>>(
        symm, c0s, c1s, c2s, c3s, sk, ck0, ck1, ck2, ck3, l0k, l1k, W, LW);
    build_cv<<<B_, 256, 0, stream>>>(
        x, corr0, corr1, corr2, corr3, vb, cb0, cb1, cb2, cb3, CV, initb);
    dim3 grid(NTILE, B_ / 128);
    main_gemm<<<grid, 256, 0, stream>>>(
        x, CV, W, LW, hb, l0hb, l1hb, partials);
    finalize_out<<<B_ / 256, 256, 0, stream>>>(initb, partials, (float*)d_out);
}

// Round 2
// 1187.205 us; speedup vs baseline: 3.7300x; 3.7300x over previous
//
#include <hip/hip_runtime.h>
#include <math.h>

#define B_    16384
#define N_    1152
#define KPAD  2496   // 1152 + 576 + 576 + 144 (cv23 3-slot) + 48 pad
#define KLOOP 256    // per-j2: 72 slots + 56 pad -> 128, x2
#define NOUT  4608
#define NTILE 36
#define LOG2F_ 0.69314718055994530942f

typedef unsigned short ushort_t;
typedef __attribute__((ext_vector_type(8))) short short8;
typedef __attribute__((ext_vector_type(4))) float floatx4;

__device__ __forceinline__ float log_cosh_f(float t) {
    float a = fabsf(t);
    return a + __logf(1.0f + __expf(-2.0f * a)) - LOG2F_;
}
__device__ __forceinline__ ushort_t bf16_rne(float f) {
    unsigned int u = __float_as_uint(f);
    return (ushort_t)((u + 0x7fffu + ((u >> 16) & 1u)) >> 16);
}
__device__ __forceinline__ float bf16_to_f(ushort_t h) {
    return __uint_as_float(((unsigned int)h) << 16);
}

typedef __attribute__((address_space(1))) const unsigned int guint;
typedef __attribute__((address_space(3))) unsigned int luint;
__device__ __forceinline__ void gload16(const ushort_t* src, ushort_t* dst) {
    __builtin_amdgcn_global_load_lds((guint*)src, (luint*)dst, 16, 0, 0);
}

// ---------------------------------------------------------------------------
// Kernel 1: gather + transpose + bf16-encode weights.
//   Wb[n][k]  bf16, n=s*8+f, k<2304 plain; k in [2304,2448): 3-slot hi/lo
//   (g=0: w_hi, g=1: w_hi, g=2: w_lo); [2448,2496): 0.
//   LWb[n][k2] bf16, k2 = j2*128 + g*24 + c (g as above), pad 0.
// One block per s.
// ---------------------------------------------------------------------------
__global__ __launch_bounds__(256) void build_w(
    const int* __restrict__ symm,
    const int* __restrict__ c0s, const int* __restrict__ c1s,
    const int* __restrict__ c2s, const int* __restrict__ c3s,
    const float* __restrict__ sk,
    const float* __restrict__ ck0, const float* __restrict__ ck1,
    const float* __restrict__ ck2, const float* __restrict__ ck3,
    const float* __restrict__ l0k, const float* __restrict__ l1k,
    ushort_t* __restrict__ Wb, ushort_t* __restrict__ LWb)
{
    __shared__ int idx[2352]; // [0,1152) symm | +576 c0 | +576 c1 | +24 c2 | +24 c3
    const int s = blockIdx.x;
    const int tid = threadIdx.x;
    for (int i = tid; i < 1152; i += 256) idx[i] = symm[s * N_ + i];
    for (int i = tid; i < 576; i += 256) idx[1152 + i] = c0s[s * 576 + i];
    for (int i = tid; i < 576; i += 256) idx[1728 + i] = c1s[s * 576 + i];
    if (tid < 24) idx[2304 + tid] = c2s[s * 24 + tid];
    else if (tid < 48) idx[2328 + (tid - 24)] = c3s[s * 24 + (tid - 24)];
    __syncthreads();
    for (int f = 0; f < 8; ++f) {
        ushort_t* wr = Wb + (size_t)(s * 8 + f) * KPAD;
        for (int k = tid; k < KPAD; k += 256) {
            ushort_t o;
            if (k < 1152)      o = bf16_rne(sk[f * N_ + idx[k]]);
            else if (k < 1728) o = bf16_rne(ck0[f * 576 + idx[576 + k]]);
            else if (k < 2304) o = bf16_rne(ck1[f * 576 + idx[k]]);
            else if (k < 2448) {
                int q = k - 2304, g = q / 48, c = q - g * 48;
                float w = (c < 24) ? ck2[f * 24 + idx[2304 + c]]
                                   : ck3[f * 24 + idx[2328 + (c - 24)]];
                ushort_t hi = bf16_rne(w);
                o = (g < 2) ? hi : bf16_rne(w - bf16_to_f(hi));
            } else o = 0;
            wr[k] = o;
        }
        ushort_t* lr = LWb + (size_t)(s * 8 + f) * KLOOP;
        for (int k2 = tid; k2 < KLOOP; k2 += 256) {
            int j2 = k2 >> 7, q = k2 & 127;
            ushort_t o = 0;
            if (q < 72) {
                int g = q / 24, c = q - g * 24;
                float w = j2 ? l1k[f * 24 + idx[2328 + c]]
                             : l0k[f * 24 + idx[2304 + c]];
                ushort_t hi = bf16_rne(w);
                o = (g < 2) ? hi : bf16_rne(w - bf16_to_f(hi));
            }
            lr[k2] = o;
        }
    }
}

// ---------------------------------------------------------------------------
// Kernel 2: augmented A matrix (bf16) + loop-cv matrix + scalar bias.
//   XA[b][k]: x | cv0 | cv1 | cv23 3-slot (g=0: cv_hi, g=1: cv_lo, g=2: cv_hi) | 0
//   CVL[b][k2]: per j2: cv_hi,cv_lo,cv_hi x24 | 0-pad
// ---------------------------------------------------------------------------
__global__ __launch_bounds__(256) void build_cv(
    const float* __restrict__ x,
    const int* __restrict__ corr0, const int* __restrict__ corr1,
    const int* __restrict__ corr2, const int* __restrict__ corr3,
    const float* __restrict__ vb,
    const float* __restrict__ cb0, const float* __restrict__ cb1,
    const float* __restrict__ cb2, const float* __restrict__ cb3,
    ushort_t* __restrict__ XA, ushort_t* __restrict__ CVL,
    float* __restrict__ initb)
{
    __shared__ float xs[N_];
    __shared__ float red[256];
    __shared__ float cvhi[48], cvlo[48];
    const int tid = threadIdx.x;
    const int b = blockIdx.x;
    ushort_t* xr = XA + (size_t)b * KPAD;

    float bias = 0.f;
    const float vb0 = vb[0], vb1 = vb[1];
    for (int i = tid; i < N_; i += 256) {
        float v = x[(size_t)b * N_ + i];
        xs[i] = v;
        bias += v * ((i & 1) ? vb1 : vb0);
        xr[i] = bf16_rne(v);
    }
    __syncthreads();
    float s0 = 0.f, s1 = 0.f, s2 = 0.f, s3 = 0.f;
    for (int c = tid; c < 576; c += 256) {
        const int* i0 = corr0 + c * 4;
        float p = xs[i0[0]] * xs[i0[1]] * xs[i0[2]] * xs[i0[3]];
        xr[1152 + c] = bf16_rne(p); s0 += p;
        const int* i1 = corr1 + c * 4;
        float q = xs[i1[0]] * xs[i1[1]] * xs[i1[2]] * xs[i1[3]];
        xr[1728 + c] = bf16_rne(q); s1 += q;
    }
    if (tid < 48) {
        int j2 = tid / 24, c = tid - j2 * 24;
        const int* ii = (j2 ? corr3 : corr2) + c * 24;
        float p = 1.f;
        for (int j = 0; j < 24; ++j) p *= xs[ii[j]];
        float hv = bf16_to_f(bf16_rne(p));
        cvhi[tid] = hv;
        cvlo[tid] = p - hv;
        if (j2) s3 = p; else s2 = p;
    }
    __syncthreads();
    for (int i = tid; i < 192; i += 256) {
        ushort_t o = 0;
        if (i < 144) {
            int g = i / 48, c = i - g * 48;
            o = bf16_rne(g == 1 ? cvlo[c] : cvhi[c]);
        }
        xr[2304 + i] = o;
    }
    ushort_t* cr = CVL + (size_t)b * KLOOP;
    for (int k2 = tid; k2 < KLOOP; k2 += 256) {
        int j2 = k2 >> 7, q = k2 & 127;
        ushort_t o = 0;
        if (q < 72) {
            int g = q / 24, c = q - g * 24;
            o = bf16_rne(g == 1 ? cvlo[j2 * 24 + c] : cvhi[j2 * 24 + c]);
        }
        cr[k2] = o;
    }
    bias += cb0[0] * s0 + cb1[0] * s1 + cb2[0] * s2 + cb3[0] * s3;
    red[tid] = bias;
    __syncthreads();
    for (int off = 128; off; off >>= 1) {
        if (tid < off) red[tid] += red[tid + off];
        __syncthreads();
    }
    if (tid == 0) initb[b] = red[0];
}

// ---------------------------------------------------------------------------
// Kernel 3: MFMA GEMM (128x128 tile, BK=64, 4 waves, 16x16x32 bf16) with
// log_cosh epilogue + fused loop-correlator mini-GEMMs.
// LDS layout: As[128 rows][64 k] | Bs[128][64], XOR-swizzled 16B granules
// (phys_granule = logical ^ (row&7)); staging pre-swizzles the GLOBAL source.
// ---------------------------------------------------------------------------
__global__ __launch_bounds__(256) void mfma_gemm(
    const ushort_t* __restrict__ XA, const ushort_t* __restrict__ Wb,
    const ushort_t* __restrict__ CVL, const ushort_t* __restrict__ LWb,
    const float* __restrict__ hidden_bias,
    const float* __restrict__ l0hb, const float* __restrict__ l1hb,
    float* __restrict__ partials)
{
    __shared__ __align__(16) ushort_t sh[16384]; // As [0,8192) | Bs [8192,16384)
    const int tid = threadIdx.x;
    const int l = tid & 63;
    const int w = tid >> 6;
    const int wm = w >> 1, wn = w & 1;
    const int lrow = l & 15, lg = l >> 4;
    const int lsw = ((l & 7) ^ (l >> 3)) * 8;  // staging src swizzle (ushort units)
    const int rb = w * 32;                     // wave staging row base

    // bijective XCD swizzle (4608 % 8 == 0), n-tile fastest within a chunk
    int bid = blockIdx.x;
    int swz = (bid & 7) * (NTILE * 128 / 8) + (bid >> 3);
    const int nt = swz % NTILE, bt = swz / NTILE;
    const int n0 = nt * 128, b0 = bt * 128;

    floatx4 acc[4][4];
#pragma unroll
    for (int i = 0; i < 4; ++i)
#pragma unroll
        for (int j = 0; j < 4; ++j) acc[i][j] = (floatx4){0.f, 0.f, 0.f, 0.f};

    for (int kc = 0; kc < KPAD / 64; ++kc) {
        const int kg = kc * 64;
#pragma unroll
        for (int i = 0; i < 4; ++i) {
            const int r0 = rb + i * 8;
            gload16(XA + (size_t)(b0 + r0 + (l >> 3)) * KPAD + kg + lsw, &sh[r0 * 64]);
            gload16(Wb + (size_t)(n0 + r0 + (l >> 3)) * KPAD + kg + lsw, &sh[8192 + r0 * 64]);
        }
        __syncthreads();
#pragma unroll
        for (int ks = 0; ks < 2; ++ks) {
            short8 af[4], bf[4];
#pragma unroll
            for (int mi = 0; mi < 4; ++mi)
                af[mi] = *(const short8*)&sh[(wm * 64 + mi * 16 + lrow) * 64 +
                                             (((ks << 2) + lg) ^ (lrow & 7)) * 8];
#pragma unroll
            for (int ni = 0; ni < 4; ++ni)
                bf[ni] = *(const short8*)&sh[8192 + (wn * 64 + ni * 16 + lrow) * 64 +
                                             (((ks << 2) + lg) ^ (lrow & 7)) * 8];
#pragma unroll
            for (int mi = 0; mi < 4; ++mi)
#pragma unroll
                for (int ni = 0; ni < 4; ++ni)
                    acc[mi][ni] = __builtin_amdgcn_mfma_f32_16x16x32_bf16(
                        af[mi], bf[ni], acc[mi][ni], 0, 0, 0);
        }
        __syncthreads();
    }

    // main log_cosh: D layout row=(l>>4)*4+reg, col=l&15; f = col&7 = l&7
    float rs[16];
    {
        const float hbv = hidden_bias[l & 7];
#pragma unroll
        for (int mi = 0; mi < 4; ++mi)
#pragma unroll
            for (int reg = 0; reg < 4; ++reg) {
                float t = 0.f;
#pragma unroll
                for (int ni = 0; ni < 4; ++ni)
                    t += log_cosh_f(acc[mi][ni][reg] + hbv);
                rs[mi * 4 + reg] = t;
            }
    }

    // loop-correlator mini-GEMMs (K=128 each, same staging scheme)
#pragma unroll 1
    for (int j2 = 0; j2 < 2; ++j2) {
        floatx4 a2[4][4];
#pragma unroll
        for (int i = 0; i < 4; ++i)
#pragma unroll
            for (int j = 0; j < 4; ++j) a2[i][j] = (floatx4){0.f, 0.f, 0.f, 0.f};
#pragma unroll 1
        for (int kc = 0; kc < 2; ++kc) {
            const int kg = j2 * 128 + kc * 64;
#pragma unroll
            for (int i = 0; i < 4; ++i) {
                const int r0 = rb + i * 8;
                gload16(CVL + (size_t)(b0 + r0 + (l >> 3)) * KLOOP + kg + lsw, &sh[r0 * 64]);
                gload16(LWb + (size_t)(n0 + r0 + (l >> 3)) * KLOOP + kg + lsw, &sh[8192 + r0 * 64]);
            }
            __syncthreads();
#pragma unroll
            for (int ks = 0; ks < 2; ++ks) {
                short8 af[4], bf[4];
#pragma unroll
                for (int mi = 0; mi < 4; ++mi)
                    af[mi] = *(const short8*)&sh[(wm * 64 + mi * 16 + lrow) * 64 +
                                                 (((ks << 2) + lg) ^ (lrow & 7)) * 8];
#pragma unroll
                for (int ni = 0; ni < 4; ++ni)
                    bf[ni] = *(const short8*)&sh[8192 + (wn * 64 + ni * 16 + lrow) * 64 +
                                                 (((ks << 2) + lg) ^ (lrow & 7)) * 8];
#pragma unroll
                for (int mi = 0; mi < 4; ++mi)
#pragma unroll
                    for (int ni = 0; ni < 4; ++ni)
                        a2[mi][ni] = __builtin_amdgcn_mfma_f32_16x16x32_bf16(
                            af[mi], bf[ni], a2[mi][ni], 0, 0, 0);
            }
            __syncthreads();
        }
        const float lbv = (j2 ? l1hb : l0hb)[l & 7];
#pragma unroll
        for (int mi = 0; mi < 4; ++mi)
#pragma unroll
            for (int reg = 0; reg < 4; ++reg) {
                float t = 0.f;
#pragma unroll
                for (int ni = 0; ni < 4; ++ni)
                    t += log_cosh_f(a2[mi][ni][reg] + lbv);
                rs[mi * 4 + reg] += t;
            }
    }

    // cross-lane/wave row reduction: red[128][17]
    float* red = (float*)sh;
    if (wn == 0) {
#pragma unroll
        for (int mi = 0; mi < 4; ++mi)
#pragma unroll
            for (int reg = 0; reg < 4; ++reg)
                red[(wm * 64 + mi * 16 + lg * 4 + reg) * 17 + lrow] = rs[mi * 4 + reg];
    }
    __syncthreads();
    if (wn == 1) {
#pragma unroll
        for (int mi = 0; mi < 4; ++mi)
#pragma unroll
            for (int reg = 0; reg < 4; ++reg)
                red[(wm * 64 + mi * 16 + lg * 4 + reg) * 17 + lrow] += rs[mi * 4 + reg];
    }
    __syncthreads();
    if (tid < 128) {
        float t = 0.f;
#pragma unroll
        for (int j = 0; j < 16; ++j) t += red[tid * 17 + j];
        partials[(size_t)nt * B_ + b0 + tid] = t;
    }
}

// ---------------------------------------------------------------------------
// Kernel 4: out[b] = initb[b] + sum over n-tiles
// ---------------------------------------------------------------------------
__global__ __launch_bounds__(256) void finalize_out(
    const float* __restrict__ initb, const float* __restrict__ partials,
    float* __restrict__ out)
{
    int b = blockIdx.x * 256 + threadIdx.x;
    float s = initb[b];
#pragma unroll
    for (int t = 0; t < NTILE; ++t) s += partials[(size_t)t * B_ + b];
    out[b] = s;
}

extern "C" void kernel_launch(void* const* d_in, const int* in_sizes, int n_in,
                              void* d_out, int out_size, void* d_ws, size_t ws_size,
                              hipStream_t stream) {
    const float* x    = (const float*)d_in[0];
    const int* symm   = (const int*)d_in[1];
    const int* corr0  = (const int*)d_in[2];
    const int* corr1  = (const int*)d_in[3];
    const int* corr2  = (const int*)d_in[4];
    const int* corr3  = (const int*)d_in[5];
    const int* c0s    = (const int*)d_in[6];
    const int* c1s    = (const int*)d_in[7];
    const int* c2s    = (const int*)d_in[8];
    const int* c3s    = (const int*)d_in[9];
    const float* hb   = (const float*)d_in[10];
    const float* sk   = (const float*)d_in[11];
    const float* vb   = (const float*)d_in[12];
    const float* cb0  = (const float*)d_in[13];
    const float* ck0  = (const float*)d_in[14];
    const float* cb1  = (const float*)d_in[15];
    const float* ck1  = (const float*)d_in[16];
    const float* cb2  = (const float*)d_in[17];
    const float* ck2  = (const float*)d_in[18];
    const float* cb3  = (const float*)d_in[19];
    const float* ck3  = (const float*)d_in[20];
    const float* l0hb = (const float*)d_in[21];
    const float* l0k  = (const float*)d_in[22];
    const float* l1hb = (const float*)d_in[23];
    const float* l1k  = (const float*)d_in[24];

    // workspace layout: ushort Wb | XA | LWb | CVL, then float initb | partials
    // total = 117,964,800 bytes
    ushort_t* wsu = (ushort_t*)d_ws;
    ushort_t* Wb  = wsu;                            // 4608*2496
    ushort_t* XA  = Wb + (size_t)NOUT * KPAD;       // 16384*2496
    ushort_t* LWb = XA + (size_t)B_ * KPAD;         // 4608*256
    ushort_t* CVL = LWb + (size_t)NOUT * KLOOP;     // 16384*256
    float* initb    = (float*)(CVL + (size_t)B_ * KLOOP);  // 16384
    float* partials = initb + B_;                          // 36*16384

    build_w<<<576, 256, 0, stream>>>(
        symm, c0s, c1s, c2s, c3s, sk, ck0, ck1, ck2, ck3, l0k, l1k, Wb, LWb);
    build_cv<<<B_, 256, 0, stream>>>(
        x, corr0, corr1, corr2, corr3, vb, cb0, cb1, cb2, cb3, XA, CVL, initb);
    mfma_gemm<<<NTILE * (B_ / 128), 256, 0, stream>>>(
        XA, Wb, CVL, LWb, hb, l0hb, l1hb, partials);
    finalize_out<<<B_ / 256, 256, 0, stream>>>(initb, partials, (float*)d_out);
}

// Round 3
// 650.171 us; speedup vs baseline: 6.8109x; 1.8260x over previous
//
#include <hip/hip_runtime.h>
#include <math.h>

#define B_    16384
#define N_    1152
#define KPAD  2496   // 1152 + 576 + 576 + 144 (cv23 3-slot) + 48 pad
#define NK    39     // KPAD/64
#define KLOOP 256    // per-j2: 72 slots + 56 pad -> 128, x2
#define NOUT  4608
#define NT2   18     // NOUT/256
#define LOG2F_ 0.69314718055994530942f

typedef unsigned short ushort_t;
typedef __attribute__((ext_vector_type(8))) short short8;
typedef __attribute__((ext_vector_type(4))) float floatx4;

__device__ __forceinline__ float log_cosh_f(float t) {
    float a = fabsf(t);
    return a + __logf(1.0f + __expf(-2.0f * a)) - LOG2F_;
}
__device__ __forceinline__ ushort_t bf16_rne(float f) {
    unsigned int u = __float_as_uint(f);
    return (ushort_t)((u + 0x7fffu + ((u >> 16) & 1u)) >> 16);
}
__device__ __forceinline__ float bf16_to_f(ushort_t h) {
    return __uint_as_float(((unsigned int)h) << 16);
}

typedef __attribute__((address_space(1))) const unsigned int guint;
typedef __attribute__((address_space(3))) unsigned int luint;
__device__ __forceinline__ void gload16(const ushort_t* src, ushort_t* dst) {
    __builtin_amdgcn_global_load_lds((guint*)src, (luint*)dst, 16, 0, 0);
}

// ---------------------------------------------------------------------------
// Kernel 1: gather + transpose + bf16-encode weights.
//   Wb[n][k]  bf16, n=s*8+f; k<2304 plain; [2304,2448) 3-slot hi/lo for cv2/cv3
//   (g=0: w_hi, g=1: w_hi, g=2: w_lo); [2448,2496) zero.
//   LWb[n][k2] bf16, k2 = j2*128 + g*24 + c, pad zero.
// idx layout matches k: [0,1152) symm | [1152,1728) c0s | [1728,2304) c1s |
// [2304,2328) c2s | [2328,2352) c3s.
// ---------------------------------------------------------------------------
__global__ __launch_bounds__(256) void build_w(
    const int* __restrict__ symm,
    const int* __restrict__ c0s, const int* __restrict__ c1s,
    const int* __restrict__ c2s, const int* __restrict__ c3s,
    const float* __restrict__ sk,
    const float* __restrict__ ck0, const float* __restrict__ ck1,
    const float* __restrict__ ck2, const float* __restrict__ ck3,
    const float* __restrict__ l0k, const float* __restrict__ l1k,
    ushort_t* __restrict__ Wb, ushort_t* __restrict__ LWb)
{
    __shared__ int idx[2352];
    const int s = blockIdx.x;
    const int tid = threadIdx.x;
    for (int i = tid; i < 1152; i += 256) idx[i] = symm[s * N_ + i];
    for (int i = tid; i < 576; i += 256) idx[1152 + i] = c0s[s * 576 + i];
    for (int i = tid; i < 576; i += 256) idx[1728 + i] = c1s[s * 576 + i];
    if (tid < 24) idx[2304 + tid] = c2s[s * 24 + tid];
    else if (tid < 48) idx[2328 + (tid - 24)] = c3s[s * 24 + (tid - 24)];
    __syncthreads();
    for (int f = 0; f < 8; ++f) {
        ushort_t* wr = Wb + (size_t)(s * 8 + f) * KPAD;
        for (int k = tid; k < KPAD; k += 256) {
            ushort_t o;
            if (k < 1152)      o = bf16_rne(sk[f * N_ + idx[k]]);
            else if (k < 1728) o = bf16_rne(ck0[f * 576 + idx[k]]);   // FIXED: idx[k]
            else if (k < 2304) o = bf16_rne(ck1[f * 576 + idx[k]]);
            else if (k < 2448) {
                int q = k - 2304, g = q / 48, c = q - g * 48;
                float w = (c < 24) ? ck2[f * 24 + idx[2304 + c]]
                                   : ck3[f * 24 + idx[2328 + (c - 24)]];
                ushort_t hi = bf16_rne(w);
                o = (g < 2) ? hi : bf16_rne(w - bf16_to_f(hi));
            } else o = 0;
            wr[k] = o;
        }
        ushort_t* lr = LWb + (size_t)(s * 8 + f) * KLOOP;
        for (int k2 = tid; k2 < KLOOP; k2 += 256) {
            int j2 = k2 >> 7, q = k2 & 127;
            ushort_t o = 0;
            if (q < 72) {
                int g = q / 24, c = q - g * 24;
                float w = j2 ? l1k[f * 24 + idx[2328 + c]]
                             : l0k[f * 24 + idx[2304 + c]];
                ushort_t hi = bf16_rne(w);
                o = (g < 2) ? hi : bf16_rne(w - bf16_to_f(hi));
            }
            lr[k2] = o;
        }
    }
}

// ---------------------------------------------------------------------------
// Kernel 2: augmented A matrix (bf16) + loop-cv matrix + scalar bias.
// ---------------------------------------------------------------------------
__global__ __launch_bounds__(256) void build_cv(
    const float* __restrict__ x,
    const int* __restrict__ corr0, const int* __restrict__ corr1,
    const int* __restrict__ corr2, const int* __restrict__ corr3,
    const float* __restrict__ vb,
    const float* __restrict__ cb0, const float* __restrict__ cb1,
    const float* __restrict__ cb2, const float* __restrict__ cb3,
    ushort_t* __restrict__ XA, ushort_t* __restrict__ CVL,
    float* __restrict__ initb)
{
    __shared__ float xs[N_];
    __shared__ float red[256];
    __shared__ float cvhi[48], cvlo[48];
    const int tid = threadIdx.x;
    const int b = blockIdx.x;
    ushort_t* xr = XA + (size_t)b * KPAD;

    float bias = 0.f;
    const float vb0 = vb[0], vb1 = vb[1];
    for (int i = tid; i < N_; i += 256) {
        float v = x[(size_t)b * N_ + i];
        xs[i] = v;
        bias += v * ((i & 1) ? vb1 : vb0);
        xr[i] = bf16_rne(v);
    }
    __syncthreads();
    float s0 = 0.f, s1 = 0.f, s2 = 0.f, s3 = 0.f;
    for (int c = tid; c < 576; c += 256) {
        const int* i0 = corr0 + c * 4;
        float p = xs[i0[0]] * xs[i0[1]] * xs[i0[2]] * xs[i0[3]];
        xr[1152 + c] = bf16_rne(p); s0 += p;
        const int* i1 = corr1 + c * 4;
        float q = xs[i1[0]] * xs[i1[1]] * xs[i1[2]] * xs[i1[3]];
        xr[1728 + c] = bf16_rne(q); s1 += q;
    }
    if (tid < 48) {
        int j2 = tid / 24, c = tid - j2 * 24;
        const int* ii = (j2 ? corr3 : corr2) + c * 24;
        float p = 1.f;
        for (int j = 0; j < 24; ++j) p *= xs[ii[j]];
        float hv = bf16_to_f(bf16_rne(p));
        cvhi[tid] = hv;
        cvlo[tid] = p - hv;
        if (j2) s3 = p; else s2 = p;
    }
    __syncthreads();
    for (int i = tid; i < 192; i += 256) {
        ushort_t o = 0;
        if (i < 144) {
            int g = i / 48, c = i - g * 48;
            o = bf16_rne(g == 1 ? cvlo[c] : cvhi[c]);
        }
        xr[2304 + i] = o;
    }
    ushort_t* cr = CVL + (size_t)b * KLOOP;
    for (int k2 = tid; k2 < KLOOP; k2 += 256) {
        int j2 = k2 >> 7, q = k2 & 127;
        ushort_t o = 0;
        if (q < 72) {
            int g = q / 24, c = q - g * 24;
            o = bf16_rne(g == 1 ? cvlo[j2 * 24 + c] : cvhi[j2 * 24 + c]);
        }
        cr[k2] = o;
    }
    bias += cb0[0] * s0 + cb1[0] * s1 + cb2[0] * s2 + cb3[0] * s3;
    red[tid] = bias;
    __syncthreads();
    for (int off = 128; off; off >>= 1) {
        if (tid < off) red[tid] += red[tid + off];
        __syncthreads();
    }
    if (tid == 0) initb[b] = red[0];
}

// ---------------------------------------------------------------------------
// Kernel 3: 256x256-tile MFMA GEMM, 8 waves (2M x 4N), BK=64, double-buffered
// global_load_lds prefetch (stage t+1 while computing t, one barrier/K-tile).
// LDS: A0|B0|A1|B1, each [256 rows][64 k] bf16, XOR-swizzled 16B granules
// (phys = logical ^ (row&7)); staging pre-swizzles the GLOBAL source.
// Epilogue: log_cosh rowsums + fused loop-correlator mini-GEMMs + reduction.
// ---------------------------------------------------------------------------
__global__ __launch_bounds__(512, 2) void mfma_gemm(
    const ushort_t* __restrict__ XA, const ushort_t* __restrict__ Wb,
    const ushort_t* __restrict__ CVL, const ushort_t* __restrict__ LWb,
    const float* __restrict__ hidden_bias,
    const float* __restrict__ l0hb, const float* __restrict__ l1hb,
    float* __restrict__ partials)
{
    __shared__ __align__(16) ushort_t sh[65536];  // 128 KiB
    ushort_t* const A0 = sh;
    ushort_t* const B0 = sh + 16384;
    ushort_t* const A1 = sh + 32768;
    ushort_t* const B1 = sh + 49152;

    const int tid = threadIdx.x;
    const int l = tid & 63, w = tid >> 6;
    const int wm = w >> 2, wn = w & 3;          // 2 M-waves x 4 N-waves
    const int lrow = l & 15, lg = l >> 4;
    const int lr8 = l >> 3;
    const int lsw = ((l & 7) ^ lr8) * 8;        // staging src swizzle (ushorts)

    // bijective XCD swizzle: 1152 blocks = 8 XCD chunks x 144
    const int bid = blockIdx.x;
    const int swz = (bid & 7) * 144 + (bid >> 3);
    const int nt = swz % NT2, bt = swz / NT2;
    const int n0 = nt * 256, b0 = bt * 256;

    const ushort_t* XAb  = XA  + (size_t)b0 * KPAD;
    const ushort_t* Wbb  = Wb  + (size_t)n0 * KPAD;
    const ushort_t* CVb  = CVL + (size_t)b0 * KLOOP;
    const ushort_t* LWbb = LWb + (size_t)n0 * KLOOP;

    floatx4 acc[8][4];

    auto STAGE = [&](const ushort_t* Ag, int sA, const ushort_t* Bg, int sB,
                     int kg, ushort_t* Ab, ushort_t* Bb) {
#pragma unroll
        for (int i = 0; i < 4; ++i) {
            const int r0 = w * 32 + i * 8;      // 8 waves x 32 rows = 256
            gload16(Ag + (size_t)(r0 + lr8) * sA + kg + lsw, &Ab[r0 * 64]);
            gload16(Bg + (size_t)(r0 + lr8) * sB + kg + lsw, &Bb[r0 * 64]);
        }
    };
    auto COMPUTE = [&](const ushort_t* Ab, const ushort_t* Bb) {
#pragma unroll
        for (int ks = 0; ks < 2; ++ks) {
            short8 af[8], bfr[4];
#pragma unroll
            for (int mi = 0; mi < 8; ++mi)
                af[mi] = *(const short8*)&Ab[(wm * 128 + mi * 16 + lrow) * 64 +
                                             (((ks << 2) + lg) ^ (lrow & 7)) * 8];
#pragma unroll
            for (int ni = 0; ni < 4; ++ni)
                bfr[ni] = *(const short8*)&Bb[(wn * 64 + ni * 16 + lrow) * 64 +
                                              (((ks << 2) + lg) ^ (lrow & 7)) * 8];
#pragma unroll
            for (int mi = 0; mi < 8; ++mi)
#pragma unroll
                for (int ni = 0; ni < 4; ++ni)
                    acc[mi][ni] = __builtin_amdgcn_mfma_f32_16x16x32_bf16(
                        af[mi], bfr[ni], acc[mi][ni], 0, 0, 0);
        }
    };

#pragma unroll
    for (int mi = 0; mi < 8; ++mi)
#pragma unroll
        for (int ni = 0; ni < 4; ++ni) acc[mi][ni] = (floatx4){0.f, 0.f, 0.f, 0.f};

    // ---- main K loop, double-buffered ----
    STAGE(XAb, KPAD, Wbb, KPAD, 0, A0, B0);
    __syncthreads();                            // implicit vmcnt(0) drain
#pragma unroll 1
    for (int t = 0; t < NK; ++t) {
        ushort_t* Ac = (t & 1) ? A1 : A0;
        ushort_t* Bc = (t & 1) ? B1 : B0;
        if (t + 1 < NK)
            STAGE(XAb, KPAD, Wbb, KPAD, (t + 1) * 64,
                  (t & 1) ? A0 : A1, (t & 1) ? B0 : B1);
        COMPUTE(Ac, Bc);
        __syncthreads();                        // drains prefetch, frees cur buf
    }

    // ---- main log_cosh rowsums (D: row=lg*4+reg within frag, col=lrow) ----
    float rs[32];
    {
        const float hbv = hidden_bias[l & 7];
#pragma unroll
        for (int mi = 0; mi < 8; ++mi)
#pragma unroll
            for (int reg = 0; reg < 4; ++reg) {
                float t = 0.f;
#pragma unroll
                for (int ni = 0; ni < 4; ++ni)
                    t += log_cosh_f(acc[mi][ni][reg] + hbv);
                rs[mi * 4 + reg] = t;
            }
    }

    // ---- loop-correlator mini-GEMMs (K=128 per j2), reuse acc + buffers ----
#pragma unroll 1
    for (int j2 = 0; j2 < 2; ++j2) {
#pragma unroll
        for (int mi = 0; mi < 8; ++mi)
#pragma unroll
            for (int ni = 0; ni < 4; ++ni) acc[mi][ni] = (floatx4){0.f, 0.f, 0.f, 0.f};
        STAGE(CVb, KLOOP, LWbb, KLOOP, j2 * 128, A0, B0);
        __syncthreads();
        STAGE(CVb, KLOOP, LWbb, KLOOP, j2 * 128 + 64, A1, B1);
        COMPUTE(A0, B0);
        __syncthreads();
        COMPUTE(A1, B1);
        const float lbv = (j2 ? l1hb : l0hb)[l & 7];
#pragma unroll
        for (int mi = 0; mi < 8; ++mi)
#pragma unroll
            for (int reg = 0; reg < 4; ++reg) {
                float t = 0.f;
#pragma unroll
                for (int ni = 0; ni < 4; ++ni)
                    t += log_cosh_f(acc[mi][ni][reg] + lbv);
                rs[mi * 4 + reg] += t;
            }
    }

    // ---- reduction: 16-lane shuffle then LDS red[256][5] ----
    __syncthreads();
    float* red = (float*)sh;
#pragma unroll
    for (int mi = 0; mi < 8; ++mi)
#pragma unroll
        for (int reg = 0; reg < 4; ++reg) {
            float v = rs[mi * 4 + reg];
            v += __shfl_xor(v, 1);
            v += __shfl_xor(v, 2);
            v += __shfl_xor(v, 4);
            v += __shfl_xor(v, 8);
            if (lrow == 0)
                red[(wm * 128 + mi * 16 + lg * 4 + reg) * 5 + wn] = v;
        }
    __syncthreads();
    if (tid < 256) {
        float t = red[tid * 5 + 0] + red[tid * 5 + 1] +
                  red[tid * 5 + 2] + red[tid * 5 + 3];
        partials[(size_t)nt * B_ + b0 + tid] = t;
    }
}

// ---------------------------------------------------------------------------
// Kernel 4: out[b] = initb[b] + sum over n-tiles
// ---------------------------------------------------------------------------
__global__ __launch_bounds__(256) void finalize_out(
    const float* __restrict__ initb, const float* __restrict__ partials,
    float* __restrict__ out)
{
    int b = blockIdx.x * 256 + threadIdx.x;
    float s = initb[b];
#pragma unroll
    for (int t = 0; t < NT2; ++t) s += partials[(size_t)t * B_ + b];
    out[b] = s;
}

extern "C" void kernel_launch(void* const* d_in, const int* in_sizes, int n_in,
                              void* d_out, int out_size, void* d_ws, size_t ws_size,
                              hipStream_t stream) {
    const float* x    = (const float*)d_in[0];
    const int* symm   = (const int*)d_in[1];
    const int* corr0  = (const int*)d_in[2];
    const int* corr1  = (const int*)d_in[3];
    const int* corr2  = (const int*)d_in[4];
    const int* corr3  = (const int*)d_in[5];
    const int* c0s    = (const int*)d_in[6];
    const int* c1s    = (const int*)d_in[7];
    const int* c2s    = (const int*)d_in[8];
    const int* c3s    = (const int*)d_in[9];
    const float* hb   = (const float*)d_in[10];
    const float* sk   = (const float*)d_in[11];
    const float* vb   = (const float*)d_in[12];
    const float* cb0  = (const float*)d_in[13];
    const float* ck0  = (const float*)d_in[14];
    const float* cb1  = (const float*)d_in[15];
    const float* ck1  = (const float*)d_in[16];
    const float* cb2  = (const float*)d_in[17];
    const float* ck2  = (const float*)d_in[18];
    const float* cb3  = (const float*)d_in[19];
    const float* ck3  = (const float*)d_in[20];
    const float* l0hb = (const float*)d_in[21];
    const float* l0k  = (const float*)d_in[22];
    const float* l1hb = (const float*)d_in[23];
    const float* l1k  = (const float*)d_in[24];

    ushort_t* wsu = (ushort_t*)d_ws;
    ushort_t* Wb  = wsu;                            // 4608*2496
    ushort_t* XA  = Wb + (size_t)NOUT * KPAD;       // 16384*2496
    ushort_t* LWb = XA + (size_t)B_ * KPAD;         // 4608*256
    ushort_t* CVL = LWb + (size_t)NOUT * KLOOP;     // 16384*256
    float* initb    = (float*)(CVL + (size_t)B_ * KLOOP);  // 16384
    float* partials = initb + B_;                          // 18*16384

    build_w<<<576, 256, 0, stream>>>(
        symm, c0s, c1s, c2s, c3s, sk, ck0, ck1, ck2, ck3, l0k, l1k, Wb, LWb);
    build_cv<<<B_, 256, 0, stream>>>(
        x, corr0, corr1, corr2, corr3, vb, cb0, cb1, cb2, cb3, XA, CVL, initb);
    mfma_gemm<<<1152, 512, 0, stream>>>(
        XA, Wb, CVL, LWb, hb, l0hb, l1hb, partials);
    finalize_out<<<B_ / 256, 256, 0, stream>>>(initb, partials, (float*)d_out);
}

// Round 4
// 621.383 us; speedup vs baseline: 7.1264x; 1.0463x over previous
//
#include <hip/hip_runtime.h>
#include <math.h>

#define B_    16384
#define N_    1152
#define KPAD  2560   // 1152 + 576 + 576 + 144 (cv23 3-slot) + 112 pad -> 80 x 32
#define NK32  80     // KPAD/32
#define KLOOP 256    // per-j2: 72 slots + 56 pad -> 128, x2
#define NOUT  4608
#define NT2   18     // NOUT/256
#define LOG2F_ 0.69314718055994530942f

typedef unsigned short ushort_t;
typedef __attribute__((ext_vector_type(8))) short short8;
typedef __attribute__((ext_vector_type(4))) float floatx4;

__device__ __forceinline__ float log_cosh_f(float t) {
    float a = fabsf(t);
    return a + __logf(1.0f + __expf(-2.0f * a)) - LOG2F_;
}
__device__ __forceinline__ ushort_t bf16_rne(float f) {
    unsigned int u = __float_as_uint(f);
    return (ushort_t)((u + 0x7fffu + ((u >> 16) & 1u)) >> 16);
}
__device__ __forceinline__ float bf16_to_f(ushort_t h) {
    return __uint_as_float(((unsigned int)h) << 16);
}

typedef __attribute__((address_space(1))) const unsigned int guint;
typedef __attribute__((address_space(3))) unsigned int luint;
__device__ __forceinline__ void gload16(const ushort_t* src, ushort_t* dst) {
    __builtin_amdgcn_global_load_lds((guint*)src, (luint*)dst, 16, 0, 0);
}

// counted-vmcnt barrier: N loads may stay in flight across the barrier
#define PIPE_WAIT(N) do {                                     \
    asm volatile("s_waitcnt vmcnt(" #N ")" ::: "memory");     \
    __builtin_amdgcn_s_barrier();                             \
    asm volatile("" ::: "memory"); } while (0)

// ---------------------------------------------------------------------------
// Kernel 1: gather + transpose + bf16-encode weights.
//   Wb[n][k] bf16, n=s*8+f; k<2304 plain; [2304,2448) 3-slot hi/lo for cv2/cv3
//   (g=0: w_hi, g=1: w_hi, g=2: w_lo); [2448,KPAD) zero.
//   LWb[n][k2] bf16, k2 = j2*128 + g*24 + c, pad zero.
// ---------------------------------------------------------------------------
__global__ __launch_bounds__(256) void build_w(
    const int* __restrict__ symm,
    const int* __restrict__ c0s, const int* __restrict__ c1s,
    const int* __restrict__ c2s, const int* __restrict__ c3s,
    const float* __restrict__ sk,
    const float* __restrict__ ck0, const float* __restrict__ ck1,
    const float* __restrict__ ck2, const float* __restrict__ ck3,
    const float* __restrict__ l0k, const float* __restrict__ l1k,
    ushort_t* __restrict__ Wb, ushort_t* __restrict__ LWb)
{
    __shared__ int idx[2352];
    const int s = blockIdx.x;
    const int tid = threadIdx.x;
    for (int i = tid; i < 1152; i += 256) idx[i] = symm[s * N_ + i];
    for (int i = tid; i < 576; i += 256) idx[1152 + i] = c0s[s * 576 + i];
    for (int i = tid; i < 576; i += 256) idx[1728 + i] = c1s[s * 576 + i];
    if (tid < 24) idx[2304 + tid] = c2s[s * 24 + tid];
    else if (tid < 48) idx[2328 + (tid - 24)] = c3s[s * 24 + (tid - 24)];
    __syncthreads();
    for (int f = 0; f < 8; ++f) {
        ushort_t* wr = Wb + (size_t)(s * 8 + f) * KPAD;
        for (int k = tid; k < KPAD; k += 256) {
            ushort_t o;
            if (k < 1152)      o = bf16_rne(sk[f * N_ + idx[k]]);
            else if (k < 1728) o = bf16_rne(ck0[f * 576 + idx[k]]);
            else if (k < 2304) o = bf16_rne(ck1[f * 576 + idx[k]]);
            else if (k < 2448) {
                int q = k - 2304, g = q / 48, c = q - g * 48;
                float w = (c < 24) ? ck2[f * 24 + idx[2304 + c]]
                                   : ck3[f * 24 + idx[2328 + (c - 24)]];
                ushort_t hi = bf16_rne(w);
                o = (g < 2) ? hi : bf16_rne(w - bf16_to_f(hi));
            } else o = 0;
            wr[k] = o;
        }
        ushort_t* lr = LWb + (size_t)(s * 8 + f) * KLOOP;
        for (int k2 = tid; k2 < KLOOP; k2 += 256) {
            int j2 = k2 >> 7, q = k2 & 127;
            ushort_t o = 0;
            if (q < 72) {
                int g = q / 24, c = q - g * 24;
                float w = j2 ? l1k[f * 24 + idx[2328 + c]]
                             : l0k[f * 24 + idx[2304 + c]];
                ushort_t hi = bf16_rne(w);
                o = (g < 2) ? hi : bf16_rne(w - bf16_to_f(hi));
            }
            lr[k2] = o;
        }
    }
}

// ---------------------------------------------------------------------------
// Kernel 2: augmented A matrix (bf16) + loop-cv matrix + scalar bias.
// ---------------------------------------------------------------------------
__global__ __launch_bounds__(256) void build_cv(
    const float* __restrict__ x,
    const int* __restrict__ corr0, const int* __restrict__ corr1,
    const int* __restrict__ corr2, const int* __restrict__ corr3,
    const float* __restrict__ vb,
    const float* __restrict__ cb0, const float* __restrict__ cb1,
    const float* __restrict__ cb2, const float* __restrict__ cb3,
    ushort_t* __restrict__ XA, ushort_t* __restrict__ CVL,
    float* __restrict__ initb)
{
    __shared__ float xs[N_];
    __shared__ float red[256];
    __shared__ float cvhi[48], cvlo[48];
    const int tid = threadIdx.x;
    const int b = blockIdx.x;
    ushort_t* xr = XA + (size_t)b * KPAD;

    float bias = 0.f;
    const float vb0 = vb[0], vb1 = vb[1];
    for (int i = tid; i < N_; i += 256) {
        float v = x[(size_t)b * N_ + i];
        xs[i] = v;
        bias += v * ((i & 1) ? vb1 : vb0);
        xr[i] = bf16_rne(v);
    }
    __syncthreads();
    float s0 = 0.f, s1 = 0.f, s2 = 0.f, s3 = 0.f;
    for (int c = tid; c < 576; c += 256) {
        const int* i0 = corr0 + c * 4;
        float p = xs[i0[0]] * xs[i0[1]] * xs[i0[2]] * xs[i0[3]];
        xr[1152 + c] = bf16_rne(p); s0 += p;
        const int* i1 = corr1 + c * 4;
        float q = xs[i1[0]] * xs[i1[1]] * xs[i1[2]] * xs[i1[3]];
        xr[1728 + c] = bf16_rne(q); s1 += q;
    }
    if (tid < 48) {
        int j2 = tid / 24, c = tid - j2 * 24;
        const int* ii = (j2 ? corr3 : corr2) + c * 24;
        float p = 1.f;
        for (int j = 0; j < 24; ++j) p *= xs[ii[j]];
        float hv = bf16_to_f(bf16_rne(p));
        cvhi[tid] = hv;
        cvlo[tid] = p - hv;
        if (j2) s3 = p; else s2 = p;
    }
    __syncthreads();
    for (int i = tid; i < KPAD - 2304; i += 256) {
        ushort_t o = 0;
        if (i < 144) {
            int g = i / 48, c = i - g * 48;
            o = bf16_rne(g == 1 ? cvlo[c] : cvhi[c]);
        }
        xr[2304 + i] = o;
    }
    ushort_t* cr = CVL + (size_t)b * KLOOP;
    for (int k2 = tid; k2 < KLOOP; k2 += 256) {
        int j2 = k2 >> 7, q = k2 & 127;
        ushort_t o = 0;
        if (q < 72) {
            int g = q / 24, c = q - g * 24;
            o = bf16_rne(g == 1 ? cvlo[j2 * 24 + c] : cvhi[j2 * 24 + c]);
        }
        cr[k2] = o;
    }
    bias += cb0[0] * s0 + cb1[0] * s1 + cb2[0] * s2 + cb3[0] * s3;
    red[tid] = bias;
    __syncthreads();
    for (int off = 128; off; off >>= 1) {
        if (tid < off) red[tid] += red[tid + off];
        __syncthreads();
    }
    if (tid == 0) initb[b] = red[0];
}

// ---------------------------------------------------------------------------
// Kernel 3: 256x256-tile MFMA GEMM, 8 waves (2M x 4N), BK=32, FOUR LDS
// buffers, counted-vmcnt pipeline: prefetch depth 3 K-tiles; vmcnt(8) at each
// raw s_barrier (never 0 in steady state). Per K-tile: 12 ds_read_b128 +
// 4 global_load_lds + 2 setprio-wrapped 16-MFMA clusters.
// LDS swizzle: phys_granule = logical ^ (row&3); gload dest linear, source
// pre-swizzled; ds_read balanced (even rows banks 0-15, odd 16-31).
// ---------------------------------------------------------------------------
__global__ __launch_bounds__(512, 2) void mfma_gemm(
    const ushort_t* __restrict__ XA, const ushort_t* __restrict__ Wb,
    const ushort_t* __restrict__ CVL, const ushort_t* __restrict__ LWb,
    const float* __restrict__ hidden_bias,
    const float* __restrict__ l0hb, const float* __restrict__ l1hb,
    float* __restrict__ partials)
{
    __shared__ __align__(16) ushort_t sh[65536];  // 4 bufs x (A 8192 | B 8192)
    ushort_t* const A0 = sh;                 ushort_t* const Bu0 = sh + 8192;
    ushort_t* const A1 = sh + 16384;         ushort_t* const Bu1 = sh + 24576;
    ushort_t* const A2 = sh + 32768;         ushort_t* const Bu2 = sh + 40960;
    ushort_t* const A3 = sh + 49152;         ushort_t* const Bu3 = sh + 57344;

    const int tid = threadIdx.x;
    const int l = tid & 63, w = tid >> 6;
    const int wm = w >> 2, wn = w & 3;          // 2 M-waves x 4 N-waves
    const int lrow = l & 15, lg = l >> 4;
    const int srow = l >> 2;                    // stage: row-within-16
    const int sgr8 = ((l & 3) ^ (srow & 3)) * 8;  // stage src swizzle (ushorts)

    // bijective XCD swizzle: 1152 blocks = 8 chunks x 144
    const int bid = blockIdx.x;
    const int swz = (bid & 7) * 144 + (bid >> 3);
    const int nt = swz % NT2, bt = swz / NT2;
    const int n0 = nt * 256, b0 = bt * 256;

    const ushort_t* XAb  = XA  + (size_t)b0 * KPAD;
    const ushort_t* Wbb  = Wb  + (size_t)n0 * KPAD;
    const ushort_t* CVb  = CVL + (size_t)b0 * KLOOP;
    const ushort_t* LWbb = LWb + (size_t)n0 * KLOOP;

    floatx4 acc[8][4];

    // stage one 256x32 tile half (A or B): 2 gloads/thread, 16 rows/wave/gload
    auto STG = [&](const ushort_t* g, int stride, int kg, ushort_t* lbase) {
#pragma unroll
        for (int i = 0; i < 2; ++i) {
            const int r0 = i * 128 + w * 16;
            gload16(g + (size_t)(r0 + srow) * stride + kg + sgr8,
                    lbase + r0 * 32);
        }
    };

    const int ga = (lg ^ (lrow & 3)) * 8;
    const int abase = (wm * 128 + lrow) * 32 + ga;
    const int bbase = (wn * 64 + lrow) * 32 + ga;

    // compute one K=32 tile (32 MFMA in 2 clusters), optionally staging next
    auto TILE = [&](const ushort_t* Ab, const ushort_t* Bb,
                    int kgn, ushort_t* An, ushort_t* Bn, bool doStage) {
        short8 af[4], af2[4], bfr[4];
#pragma unroll
        for (int mi = 0; mi < 4; ++mi)
            af[mi] = *(const short8*)(Ab + abase + mi * 512);
#pragma unroll
        for (int ni = 0; ni < 4; ++ni)
            bfr[ni] = *(const short8*)(Bb + bbase + ni * 512);
        if (doStage) { STG(XAb, KPAD, kgn, An); STG(Wbb, KPAD, kgn, Bn); }
        asm volatile("" ::: "memory");
        __builtin_amdgcn_s_setprio(1);
#pragma unroll
        for (int mi = 0; mi < 4; ++mi)
#pragma unroll
            for (int ni = 0; ni < 4; ++ni)
                acc[mi][ni] = __builtin_amdgcn_mfma_f32_16x16x32_bf16(
                    af[mi], bfr[ni], acc[mi][ni], 0, 0, 0);
        __builtin_amdgcn_s_setprio(0);
#pragma unroll
        for (int mi = 0; mi < 4; ++mi)
            af2[mi] = *(const short8*)(Ab + abase + 2048 + mi * 512);
        __builtin_amdgcn_s_setprio(1);
#pragma unroll
        for (int mi = 0; mi < 4; ++mi)
#pragma unroll
            for (int ni = 0; ni < 4; ++ni)
                acc[mi + 4][ni] = __builtin_amdgcn_mfma_f32_16x16x32_bf16(
                    af2[mi], bfr[ni], acc[mi + 4][ni], 0, 0, 0);
        __builtin_amdgcn_s_setprio(0);
    };

#pragma unroll
    for (int mi = 0; mi < 8; ++mi)
#pragma unroll
        for (int ni = 0; ni < 4; ++ni) acc[mi][ni] = (floatx4){0.f, 0.f, 0.f, 0.f};

    // ---- main K loop: prologue stages T0..T2, steady state 3 tiles ahead ----
    STG(XAb, KPAD, 0, A0);  STG(Wbb, KPAD, 0, Bu0);
    STG(XAb, KPAD, 32, A1); STG(Wbb, KPAD, 32, Bu1);
    STG(XAb, KPAD, 64, A2); STG(Wbb, KPAD, 64, Bu2);
#pragma unroll 1
    for (int tt = 0; tt < 19; ++tt) {
        const int t = tt * 4;
        PIPE_WAIT(8); TILE(A0, Bu0, (t + 3) * 32, A3, Bu3, true);
        PIPE_WAIT(8); TILE(A1, Bu1, (t + 4) * 32, A0, Bu0, true);
        PIPE_WAIT(8); TILE(A2, Bu2, (t + 5) * 32, A1, Bu1, true);
        PIPE_WAIT(8); TILE(A3, Bu3, (t + 6) * 32, A2, Bu2, true);
    }
    PIPE_WAIT(8); TILE(A0, Bu0, 79 * 32, A3, Bu3, true);   // t=76
    PIPE_WAIT(8); TILE(A1, Bu1, 0, A0, Bu0, false);        // t=77
    PIPE_WAIT(4); TILE(A2, Bu2, 0, A0, Bu0, false);        // t=78
    PIPE_WAIT(0); TILE(A3, Bu3, 0, A0, Bu0, false);        // t=79

    // ---- main log_cosh rowsums (D: row=lg*4+reg within frag, col=lrow) ----
    float rs[32];
    {
        const float hbv = hidden_bias[l & 7];
#pragma unroll
        for (int mi = 0; mi < 8; ++mi)
#pragma unroll
            for (int reg = 0; reg < 4; ++reg) {
                float t = 0.f;
#pragma unroll
                for (int ni = 0; ni < 4; ++ni)
                    t += log_cosh_f(acc[mi][ni][reg] + hbv);
                rs[mi * 4 + reg] = t;
            }
    }

    // ---- loop-correlator mini-GEMMs (K=128 per j2): simple drain staging ----
#pragma unroll 1
    for (int j2 = 0; j2 < 2; ++j2) {
#pragma unroll
        for (int mi = 0; mi < 8; ++mi)
#pragma unroll
            for (int ni = 0; ni < 4; ++ni) acc[mi][ni] = (floatx4){0.f, 0.f, 0.f, 0.f};
        __syncthreads();   // all waves done reading buffers
        STG(CVb, KLOOP, j2 * 128 +  0, A0); STG(LWbb, KLOOP, j2 * 128 +  0, Bu0);
        STG(CVb, KLOOP, j2 * 128 + 32, A1); STG(LWbb, KLOOP, j2 * 128 + 32, Bu1);
        STG(CVb, KLOOP, j2 * 128 + 64, A2); STG(LWbb, KLOOP, j2 * 128 + 64, Bu2);
        STG(CVb, KLOOP, j2 * 128 + 96, A3); STG(LWbb, KLOOP, j2 * 128 + 96, Bu3);
        __syncthreads();   // drains vmcnt(0): all staged & visible
        TILE(A0, Bu0, 0, A0, Bu0, false);
        TILE(A1, Bu1, 0, A0, Bu0, false);
        TILE(A2, Bu2, 0, A0, Bu0, false);
        TILE(A3, Bu3, 0, A0, Bu0, false);
        const float lbv = (j2 ? l1hb : l0hb)[l & 7];
#pragma unroll
        for (int mi = 0; mi < 8; ++mi)
#pragma unroll
            for (int reg = 0; reg < 4; ++reg) {
                float t = 0.f;
#pragma unroll
                for (int ni = 0; ni < 4; ++ni)
                    t += log_cosh_f(acc[mi][ni][reg] + lbv);
                rs[mi * 4 + reg] += t;
            }
    }

    // ---- reduction: 16-lane shuffle then LDS red[256][5] ----
    __syncthreads();
    float* red = (float*)sh;
#pragma unroll
    for (int mi = 0; mi < 8; ++mi)
#pragma unroll
        for (int reg = 0; reg < 4; ++reg) {
            float v = rs[mi * 4 + reg];
            v += __shfl_xor(v, 1);
            v += __shfl_xor(v, 2);
            v += __shfl_xor(v, 4);
            v += __shfl_xor(v, 8);
            if (lrow == 0)
                red[(wm * 128 + mi * 16 + lg * 4 + reg) * 5 + wn] = v;
        }
    __syncthreads();
    if (tid < 256) {
        float t = red[tid * 5 + 0] + red[tid * 5 + 1] +
                  red[tid * 5 + 2] + red[tid * 5 + 3];
        partials[(size_t)nt * B_ + b0 + tid] = t;
    }
}

// ---------------------------------------------------------------------------
// Kernel 4: out[b] = initb[b] + sum over n-tiles
// ---------------------------------------------------------------------------
__global__ __launch_bounds__(256) void finalize_out(
    const float* __restrict__ initb, const float* __restrict__ partials,
    float* __restrict__ out)
{
    int b = blockIdx.x * 256 + threadIdx.x;
    float s = initb[b];
#pragma unroll
    for (int t = 0; t < NT2; ++t) s += partials[(size_t)t * B_ + b];
    out[b] = s;
}

extern "C" void kernel_launch(void* const* d_in, const int* in_sizes, int n_in,
                              void* d_out, int out_size, void* d_ws, size_t ws_size,
                              hipStream_t stream) {
    const float* x    = (const float*)d_in[0];
    const int* symm   = (const int*)d_in[1];
    const int* corr0  = (const int*)d_in[2];
    const int* corr1  = (const int*)d_in[3];
    const int* corr2  = (const int*)d_in[4];
    const int* corr3  = (const int*)d_in[5];
    const int* c0s    = (const int*)d_in[6];
    const int* c1s    = (const int*)d_in[7];
    const int* c2s    = (const int*)d_in[8];
    const int* c3s    = (const int*)d_in[9];
    const float* hb   = (const float*)d_in[10];
    const float* sk   = (const float*)d_in[11];
    const float* vb   = (const float*)d_in[12];
    const float* cb0  = (const float*)d_in[13];
    const float* ck0  = (const float*)d_in[14];
    const float* cb1  = (const float*)d_in[15];
    const float* ck1  = (const float*)d_in[16];
    const float* cb2  = (const float*)d_in[17];
    const float* ck2  = (const float*)d_in[18];
    const float* cb3  = (const float*)d_in[19];
    const float* ck3  = (const float*)d_in[20];
    const float* l0hb = (const float*)d_in[21];
    const float* l0k  = (const float*)d_in[22];
    const float* l1hb = (const float*)d_in[23];
    const float* l1k  = (const float*)d_in[24];

    ushort_t* wsu = (ushort_t*)d_ws;
    ushort_t* Wb  = wsu;                            // 4608*2560
    ushort_t* XA  = Wb + (size_t)NOUT * KPAD;       // 16384*2560
    ushort_t* LWb = XA + (size_t)B_ * KPAD;         // 4608*256
    ushort_t* CVL = LWb + (size_t)NOUT * KLOOP;     // 16384*256
    float* initb    = (float*)(CVL + (size_t)B_ * KLOOP);  // 16384
    float* partials = initb + B_;                          // 18*16384

    build_w<<<576, 256, 0, stream>>>(
        symm, c0s, c1s, c2s, c3s, sk, ck0, ck1, ck2, ck3, l0k, l1k, Wb, LWb);
    build_cv<<<B_, 256, 0, stream>>>(
        x, corr0, corr1, corr2, corr3, vb, cb0, cb1, cb2, cb3, XA, CVL, initb);
    mfma_gemm<<<1152, 512, 0, stream>>>(
        XA, Wb, CVL, LWb, hb, l0hb, l1hb, partials);
    finalize_out<<<B_ / 256, 256, 0, stream>>>(initb, partials, (float*)d_out);
}

// Round 5
// 613.196 us; speedup vs baseline: 7.2216x; 1.0134x over previous
//
#include <hip/hip_runtime.h>
#include <math.h>

#define B_    16384
#define N_    1152
#define KPAD  2464   // 1152 + 576 + 576 + 144 (cv23 3-slot) + 16 pad -> 77 x 32
#define NK32  77     // KPAD/32
#define KLOOP 256    // per-j2: 72 slots + 56 pad -> 128, x2
#define NOUT  4608
#define NT2   18     // NOUT/256
#define LOG2F_ 0.69314718055994530942f

typedef unsigned short ushort_t;
typedef __attribute__((ext_vector_type(8))) short short8;
typedef __attribute__((ext_vector_type(4))) float floatx4;

__device__ __forceinline__ float log_cosh_f(float t) {
    float a = fabsf(t);
    return a + __logf(1.0f + __expf(-2.0f * a)) - LOG2F_;
}
__device__ __forceinline__ ushort_t bf16_rne(float f) {
    unsigned int u = __float_as_uint(f);
    return (ushort_t)((u + 0x7fffu + ((u >> 16) & 1u)) >> 16);
}
__device__ __forceinline__ float bf16_to_f(ushort_t h) {
    return __uint_as_float(((unsigned int)h) << 16);
}

typedef __attribute__((address_space(1))) const unsigned int guint;
typedef __attribute__((address_space(3))) unsigned int luint;
__device__ __forceinline__ void gload16(const ushort_t* src, ushort_t* dst) {
    __builtin_amdgcn_global_load_lds((guint*)src, (luint*)dst, 16, 0, 0);
}

// counted-vmcnt tile entry: this wave's oldest loads must be done, then sync
#define PIPE_WAIT(N) do {                                     \
    asm volatile("s_waitcnt vmcnt(" #N ")" ::: "memory");     \
    __builtin_amdgcn_s_barrier();                             \
    asm volatile("" ::: "memory"); } while (0)

// ---------------------------------------------------------------------------
// Kernel 1: gather + transpose + bf16-encode weights.
//   Wb[n][k] bf16, n=s*8+f; k<2304 plain; [2304,2448) 3-slot hi/lo for cv2/cv3
//   (g=0: w_hi, g=1: w_hi, g=2: w_lo); [2448,KPAD) zero.
//   LWb[n][k2] bf16, k2 = j2*128 + g*24 + c, pad zero.
// ---------------------------------------------------------------------------
__global__ __launch_bounds__(256) void build_w(
    const int* __restrict__ symm,
    const int* __restrict__ c0s, const int* __restrict__ c1s,
    const int* __restrict__ c2s, const int* __restrict__ c3s,
    const float* __restrict__ sk,
    const float* __restrict__ ck0, const float* __restrict__ ck1,
    const float* __restrict__ ck2, const float* __restrict__ ck3,
    const float* __restrict__ l0k, const float* __restrict__ l1k,
    ushort_t* __restrict__ Wb, ushort_t* __restrict__ LWb)
{
    __shared__ int idx[2352];
    const int s = blockIdx.x;
    const int tid = threadIdx.x;
    for (int i = tid; i < 1152; i += 256) idx[i] = symm[s * N_ + i];
    for (int i = tid; i < 576; i += 256) idx[1152 + i] = c0s[s * 576 + i];
    for (int i = tid; i < 576; i += 256) idx[1728 + i] = c1s[s * 576 + i];
    if (tid < 24) idx[2304 + tid] = c2s[s * 24 + tid];
    else if (tid < 48) idx[2328 + (tid - 24)] = c3s[s * 24 + (tid - 24)];
    __syncthreads();
    for (int f = 0; f < 8; ++f) {
        ushort_t* wr = Wb + (size_t)(s * 8 + f) * KPAD;
        for (int k = tid; k < KPAD; k += 256) {
            ushort_t o;
            if (k < 1152)      o = bf16_rne(sk[f * N_ + idx[k]]);
            else if (k < 1728) o = bf16_rne(ck0[f * 576 + idx[k]]);
            else if (k < 2304) o = bf16_rne(ck1[f * 576 + idx[k]]);
            else if (k < 2448) {
                int q = k - 2304, g = q / 48, c = q - g * 48;
                float w = (c < 24) ? ck2[f * 24 + idx[2304 + c]]
                                   : ck3[f * 24 + idx[2328 + (c - 24)]];
                ushort_t hi = bf16_rne(w);
                o = (g < 2) ? hi : bf16_rne(w - bf16_to_f(hi));
            } else o = 0;
            wr[k] = o;
        }
        ushort_t* lr = LWb + (size_t)(s * 8 + f) * KLOOP;
        for (int k2 = tid; k2 < KLOOP; k2 += 256) {
            int j2 = k2 >> 7, q = k2 & 127;
            ushort_t o = 0;
            if (q < 72) {
                int g = q / 24, c = q - g * 24;
                float w = j2 ? l1k[f * 24 + idx[2328 + c]]
                             : l0k[f * 24 + idx[2304 + c]];
                ushort_t hi = bf16_rne(w);
                o = (g < 2) ? hi : bf16_rne(w - bf16_to_f(hi));
            }
            lr[k2] = o;
        }
    }
}

// ---------------------------------------------------------------------------
// Kernel 2: augmented A matrix (bf16) + loop-cv matrix + scalar bias.
// ---------------------------------------------------------------------------
__global__ __launch_bounds__(256) void build_cv(
    const float* __restrict__ x,
    const int* __restrict__ corr0, const int* __restrict__ corr1,
    const int* __restrict__ corr2, const int* __restrict__ corr3,
    const float* __restrict__ vb,
    const float* __restrict__ cb0, const float* __restrict__ cb1,
    const float* __restrict__ cb2, const float* __restrict__ cb3,
    ushort_t* __restrict__ XA, ushort_t* __restrict__ CVL,
    float* __restrict__ initb)
{
    __shared__ float xs[N_];
    __shared__ float red[256];
    __shared__ float cvhi[48], cvlo[48];
    const int tid = threadIdx.x;
    const int b = blockIdx.x;
    ushort_t* xr = XA + (size_t)b * KPAD;

    float bias = 0.f;
    const float vb0 = vb[0], vb1 = vb[1];
    for (int i = tid; i < N_; i += 256) {
        float v = x[(size_t)b * N_ + i];
        xs[i] = v;
        bias += v * ((i & 1) ? vb1 : vb0);
        xr[i] = bf16_rne(v);
    }
    __syncthreads();
    float s0 = 0.f, s1 = 0.f, s2 = 0.f, s3 = 0.f;
    for (int c = tid; c < 576; c += 256) {
        const int* i0 = corr0 + c * 4;
        float p = xs[i0[0]] * xs[i0[1]] * xs[i0[2]] * xs[i0[3]];
        xr[1152 + c] = bf16_rne(p); s0 += p;
        const int* i1 = corr1 + c * 4;
        float q = xs[i1[0]] * xs[i1[1]] * xs[i1[2]] * xs[i1[3]];
        xr[1728 + c] = bf16_rne(q); s1 += q;
    }
    if (tid < 48) {
        int j2 = tid / 24, c = tid - j2 * 24;
        const int* ii = (j2 ? corr3 : corr2) + c * 24;
        float p = 1.f;
        for (int j = 0; j < 24; ++j) p *= xs[ii[j]];
        float hv = bf16_to_f(bf16_rne(p));
        cvhi[tid] = hv;
        cvlo[tid] = p - hv;
        if (j2) s3 = p; else s2 = p;
    }
    __syncthreads();
    for (int i = tid; i < KPAD - 2304; i += 256) {
        ushort_t o = 0;
        if (i < 144) {
            int g = i / 48, c = i - g * 48;
            o = bf16_rne(g == 1 ? cvlo[c] : cvhi[c]);
        }
        xr[2304 + i] = o;
    }
    ushort_t* cr = CVL + (size_t)b * KLOOP;
    for (int k2 = tid; k2 < KLOOP; k2 += 256) {
        int j2 = k2 >> 7, q = k2 & 127;
        ushort_t o = 0;
        if (q < 72) {
            int g = q / 24, c = q - g * 24;
            o = bf16_rne(g == 1 ? cvlo[j2 * 24 + c] : cvhi[j2 * 24 + c]);
        }
        cr[k2] = o;
    }
    bias += cb0[0] * s0 + cb1[0] * s1 + cb2[0] * s2 + cb3[0] * s3;
    red[tid] = bias;
    __syncthreads();
    for (int off = 128; off; off >>= 1) {
        if (tid < off) red[tid] += red[tid + off];
        __syncthreads();
    }
    if (tid == 0) initb[b] = red[0];
}

// ---------------------------------------------------------------------------
// Kernel 3: 256x256-tile MFMA GEMM, 8 waves (2M x 4N), BK=32, 4 LDS buffers,
// counted-vmcnt pipeline (3 tiles ahead, vmcnt(8) per tile, never 0 steady).
// Each K-tile = 2 barriered phases: {ds_reads || 1 stage-half -> barrier ->
// lgkmcnt(0)+sched_barrier -> setprio(1) 16 MFMA setprio(0) -> barrier}.
// LDS swizzle (octet-conflict-free for 64B rows): phys_granule = lg ^
// ((row>>1)&3); quad=(4r+p)%8 hits all 8 quads per 8-lane group. gload dest
// linear; SOURCE pre-swizzled with the same involution (rule #21).
// ---------------------------------------------------------------------------
__global__ __launch_bounds__(512, 2) void mfma_gemm(
    const ushort_t* __restrict__ XA, const ushort_t* __restrict__ Wb,
    const ushort_t* __restrict__ CVL, const ushort_t* __restrict__ LWb,
    const float* __restrict__ hidden_bias,
    const float* __restrict__ l0hb, const float* __restrict__ l1hb,
    float* __restrict__ partials)
{
    __shared__ __align__(16) ushort_t sh[65536];  // 4 bufs x (A 8192 | B 8192)
    ushort_t* const A0 = sh;                 ushort_t* const Bu0 = sh + 8192;
    ushort_t* const A1 = sh + 16384;         ushort_t* const Bu1 = sh + 24576;
    ushort_t* const A2 = sh + 32768;         ushort_t* const Bu2 = sh + 40960;
    ushort_t* const A3 = sh + 49152;         ushort_t* const Bu3 = sh + 57344;

    const int tid = threadIdx.x;
    const int l = tid & 63, w = tid >> 6;
    const int wm = w >> 2, wn = w & 3;          // 2 M-waves x 4 N-waves
    const int lrow = l & 15, lg = l >> 4;
    const int srow = l >> 2;                    // stage: row-within-16
    const int sgr8 = ((l & 3) ^ ((srow >> 1) & 3)) * 8;  // stage src swizzle

    // bijective XCD swizzle: 1152 blocks = 8 chunks x 144
    const int bid = blockIdx.x;
    const int swz = (bid & 7) * 144 + (bid >> 3);
    const int nt = swz % NT2, bt = swz / NT2;
    const int n0 = nt * 256, b0 = bt * 256;

    const ushort_t* XAb  = XA  + (size_t)b0 * KPAD;
    const ushort_t* Wbb  = Wb  + (size_t)n0 * KPAD;
    const ushort_t* CVb  = CVL + (size_t)b0 * KLOOP;
    const ushort_t* LWbb = LWb + (size_t)n0 * KLOOP;

    floatx4 acc[8][4];

    // stage one 256x32 half-matrix (A or B): 2 gloads/thread
    auto STG = [&](const ushort_t* g, int stride, int kg, ushort_t* lbase) {
#pragma unroll
        for (int i = 0; i < 2; ++i) {
            const int r0 = i * 128 + w * 16;
            gload16(g + (size_t)(r0 + srow) * stride + kg + sgr8,
                    lbase + r0 * 32);
        }
    };

    const int ga = (lg ^ ((lrow >> 1) & 3)) * 8;   // read-side swizzle
    const int abase = (wm * 128 + lrow) * 32 + ga;
    const int bbase = (wn * 64 + lrow) * 32 + ga;

    // one K=32 tile as two barriered phases
    auto TILE2 = [&](const ushort_t* Ab, const ushort_t* Bb,
                     int kgn, ushort_t* An, ushort_t* Bn, bool doStage) {
        short8 af[4], af2[4], bfr[4];
        // ---- phase 1: reads (af m0..3 + bfr) || stage A(t+3) ----
#pragma unroll
        for (int mi = 0; mi < 4; ++mi)
            af[mi] = *(const short8*)(Ab + abase + mi * 512);
#pragma unroll
        for (int ni = 0; ni < 4; ++ni)
            bfr[ni] = *(const short8*)(Bb + bbase + ni * 512);
        if (doStage) STG(XAb, KPAD, kgn, An);
        __builtin_amdgcn_sched_barrier(0);
        __builtin_amdgcn_s_barrier();
        asm volatile("s_waitcnt lgkmcnt(0)" ::: "memory");
        __builtin_amdgcn_sched_barrier(0);
        __builtin_amdgcn_s_setprio(1);
#pragma unroll
        for (int mi = 0; mi < 4; ++mi)
#pragma unroll
            for (int ni = 0; ni < 4; ++ni)
                acc[mi][ni] = __builtin_amdgcn_mfma_f32_16x16x32_bf16(
                    af[mi], bfr[ni], acc[mi][ni], 0, 0, 0);
        __builtin_amdgcn_s_setprio(0);
        __builtin_amdgcn_s_barrier();
        // ---- phase 2: reads (af m4..7) || stage B(t+3) ----
#pragma unroll
        for (int mi = 0; mi < 4; ++mi)
            af2[mi] = *(const short8*)(Ab + abase + 2048 + mi * 512);
        if (doStage) STG(Wbb, KPAD, kgn, Bn);
        __builtin_amdgcn_sched_barrier(0);
        __builtin_amdgcn_s_barrier();
        asm volatile("s_waitcnt lgkmcnt(0)" ::: "memory");
        __builtin_amdgcn_sched_barrier(0);
        __builtin_amdgcn_s_setprio(1);
#pragma unroll
        for (int mi = 0; mi < 4; ++mi)
#pragma unroll
            for (int ni = 0; ni < 4; ++ni)
                acc[mi + 4][ni] = __builtin_amdgcn_mfma_f32_16x16x32_bf16(
                    af2[mi], bfr[ni], acc[mi + 4][ni], 0, 0, 0);
        __builtin_amdgcn_s_setprio(0);
        __builtin_amdgcn_s_barrier();
    };

#pragma unroll
    for (int mi = 0; mi < 8; ++mi)
#pragma unroll
        for (int ni = 0; ni < 4; ++ni) acc[mi][ni] = (floatx4){0.f, 0.f, 0.f, 0.f};

    // ---- main K loop: 77 tiles, prefetch depth 3 ----
    STG(XAb, KPAD, 0, A0);  STG(Wbb, KPAD, 0, Bu0);
    STG(XAb, KPAD, 32, A1); STG(Wbb, KPAD, 32, Bu1);
    STG(XAb, KPAD, 64, A2); STG(Wbb, KPAD, 64, Bu2);
#pragma unroll 1
    for (int tt = 0; tt < 18; ++tt) {
        const int t = tt * 4;
        PIPE_WAIT(8); TILE2(A0, Bu0, (t + 3) * 32, A3, Bu3, true);
        PIPE_WAIT(8); TILE2(A1, Bu1, (t + 4) * 32, A0, Bu0, true);
        PIPE_WAIT(8); TILE2(A2, Bu2, (t + 5) * 32, A1, Bu1, true);
        PIPE_WAIT(8); TILE2(A3, Bu3, (t + 6) * 32, A2, Bu2, true);
    }
    PIPE_WAIT(8); TILE2(A0, Bu0, 75 * 32, A3, Bu3, true);   // t=72
    PIPE_WAIT(8); TILE2(A1, Bu1, 76 * 32, A0, Bu0, true);   // t=73
    PIPE_WAIT(8); TILE2(A2, Bu2, 0, A1, Bu1, false);        // t=74
    PIPE_WAIT(4); TILE2(A3, Bu3, 0, A1, Bu1, false);        // t=75
    PIPE_WAIT(0); TILE2(A0, Bu0, 0, A1, Bu1, false);        // t=76

    // ---- main log_cosh rowsums (D: row=lg*4+reg within frag, col=lrow) ----
    float rs[32];
    {
        const float hbv = hidden_bias[l & 7];
#pragma unroll
        for (int mi = 0; mi < 8; ++mi)
#pragma unroll
            for (int reg = 0; reg < 4; ++reg) {
                float t = 0.f;
#pragma unroll
                for (int ni = 0; ni < 4; ++ni)
                    t += log_cosh_f(acc[mi][ni][reg] + hbv);
                rs[mi * 4 + reg] = t;
            }
    }

    // ---- loop-correlator mini-GEMMs (K=128 per j2): drain staging ----
#pragma unroll 1
    for (int j2 = 0; j2 < 2; ++j2) {
#pragma unroll
        for (int mi = 0; mi < 8; ++mi)
#pragma unroll
            for (int ni = 0; ni < 4; ++ni) acc[mi][ni] = (floatx4){0.f, 0.f, 0.f, 0.f};
        __syncthreads();   // all waves done reading buffers
        STG(CVb, KLOOP, j2 * 128 +  0, A0); STG(LWbb, KLOOP, j2 * 128 +  0, Bu0);
        STG(CVb, KLOOP, j2 * 128 + 32, A1); STG(LWbb, KLOOP, j2 * 128 + 32, Bu1);
        STG(CVb, KLOOP, j2 * 128 + 64, A2); STG(LWbb, KLOOP, j2 * 128 + 64, Bu2);
        STG(CVb, KLOOP, j2 * 128 + 96, A3); STG(LWbb, KLOOP, j2 * 128 + 96, Bu3);
        __syncthreads();   // drains vmcnt(0): all staged & visible
        TILE2(A0, Bu0, 0, A1, Bu1, false);
        TILE2(A1, Bu1, 0, A1, Bu1, false);
        TILE2(A2, Bu2, 0, A1, Bu1, false);
        TILE2(A3, Bu3, 0, A1, Bu1, false);
        const float lbv = (j2 ? l1hb : l0hb)[l & 7];
#pragma unroll
        for (int mi = 0; mi < 8; ++mi)
#pragma unroll
            for (int reg = 0; reg < 4; ++reg) {
                float t = 0.f;
#pragma unroll
                for (int ni = 0; ni < 4; ++ni)
                    t += log_cosh_f(acc[mi][ni][reg] + lbv);
                rs[mi * 4 + reg] += t;
            }
    }

    // ---- reduction: 16-lane shuffle then LDS red[256][5] ----
    __syncthreads();
    float* red = (float*)sh;
#pragma unroll
    for (int mi = 0; mi < 8; ++mi)
#pragma unroll
        for (int reg = 0; reg < 4; ++reg) {
            float v = rs[mi * 4 + reg];
            v += __shfl_xor(v, 1);
            v += __shfl_xor(v, 2);
            v += __shfl_xor(v, 4);
            v += __shfl_xor(v, 8);
            if (lrow == 0)
                red[(wm * 128 + mi * 16 + lg * 4 + reg) * 5 + wn] = v;
        }
    __syncthreads();
    if (tid < 256) {
        float t = red[tid * 5 + 0] + red[tid * 5 + 1] +
                  red[tid * 5 + 2] + red[tid * 5 + 3];
        partials[(size_t)nt * B_ + b0 + tid] = t;
    }
}

// ---------------------------------------------------------------------------
// Kernel 4: out[b] = initb[b] + sum over n-tiles
// ---------------------------------------------------------------------------
__global__ __launch_bounds__(256) void finalize_out(
    const float* __restrict__ initb, const float* __restrict__ partials,
    float* __restrict__ out)
{
    int b = blockIdx.x * 256 + threadIdx.x;
    float s = initb[b];
#pragma unroll
    for (int t = 0; t < NT2; ++t) s += partials[(size_t)t * B_ + b];
    out[b] = s;
}

extern "C" void kernel_launch(void* const* d_in, const int* in_sizes, int n_in,
                              void* d_out, int out_size, void* d_ws, size_t ws_size,
                              hipStream_t stream) {
    const float* x    = (const float*)d_in[0];
    const int* symm   = (const int*)d_in[1];
    const int* corr0  = (const int*)d_in[2];
    const int* corr1  = (const int*)d_in[3];
    const int* corr2  = (const int*)d_in[4];
    const int* corr3  = (const int*)d_in[5];
    const int* c0s    = (const int*)d_in[6];
    const int* c1s    = (const int*)d_in[7];
    const int* c2s    = (const int*)d_in[8];
    const int* c3s    = (const int*)d_in[9];
    const float* hb   = (const float*)d_in[10];
    const float* sk   = (const float*)d_in[11];
    const float* vb   = (const float*)d_in[12];
    const float* cb0  = (const float*)d_in[13];
    const float* ck0  = (const float*)d_in[14];
    const float* cb1  = (const float*)d_in[15];
    const float* ck1  = (const float*)d_in[16];
    const float* cb2  = (const float*)d_in[17];
    const float* ck2  = (const float*)d_in[18];
    const float* cb3  = (const float*)d_in[19];
    const float* ck3  = (const float*)d_in[20];
    const float* l0hb = (const float*)d_in[21];
    const float* l0k  = (const float*)d_in[22];
    const float* l1hb = (const float*)d_in[23];
    const float* l1k  = (const float*)d_in[24];

    ushort_t* wsu = (ushort_t*)d_ws;
    ushort_t* Wb  = wsu;                            // 4608*2464
    ushort_t* XA  = Wb + (size_t)NOUT * KPAD;       // 16384*2464
    ushort_t* LWb = XA + (size_t)B_ * KPAD;         // 4608*256
    ushort_t* CVL = LWb + (size_t)NOUT * KLOOP;     // 16384*256
    float* initb    = (float*)(CVL + (size_t)B_ * KLOOP);  // 16384
    float* partials = initb + B_;                          // 18*16384

    build_w<<<576, 256, 0, stream>>>(
        symm, c0s, c1s, c2s, c3s, sk, ck0, ck1, ck2, ck3, l0k, l1k, Wb, LWb);
    build_cv<<<B_, 256, 0, stream>>>(
        x, corr0, corr1, corr2, corr3, vb, cb0, cb1, cb2, cb3, XA, CVL, initb);
    mfma_gemm<<<1152, 512, 0, stream>>>(
        XA, Wb, CVL, LWb, hb, l0hb, l1hb, partials);
    finalize_out<<<B_ / 256, 256, 0, stream>>>(initb, partials, (float*)d_out);
}

// Round 6
// 610.853 us; speedup vs baseline: 7.2493x; 1.0038x over previous
//
#include <hip/hip_runtime.h>
#include <math.h>

#define B_    16384
#define N_    1152
#define KPAD  2496   // 1152 + 576 + 576 + 144 (cv23 3-slot) + 48 pad -> 39 x 64
#define NKT   39     // K-tiles of 64
#define KLOOP 256    // per-j2: 72 slots + 56 pad -> 128, x2
#define NOUT  4608
#define NT2   18     // NOUT/256
#define LOG2F_ 0.69314718055994530942f

typedef unsigned short ushort_t;
typedef __attribute__((ext_vector_type(8))) short short8;
typedef __attribute__((ext_vector_type(4))) float floatx4;

__device__ __forceinline__ float log_cosh_f(float t) {
    float a = fabsf(t);
    return a + __logf(1.0f + __expf(-2.0f * a)) - LOG2F_;
}
__device__ __forceinline__ ushort_t bf16_rne(float f) {
    unsigned int u = __float_as_uint(f);
    return (ushort_t)((u + 0x7fffu + ((u >> 16) & 1u)) >> 16);
}
__device__ __forceinline__ float bf16_to_f(ushort_t h) {
    return __uint_as_float(((unsigned int)h) << 16);
}

typedef __attribute__((address_space(1))) const unsigned int guint;
typedef __attribute__((address_space(3))) unsigned int luint;
__device__ __forceinline__ void gload16(const ushort_t* src, ushort_t* dst) {
    __builtin_amdgcn_global_load_lds((guint*)src, (luint*)dst, 16, 0, 0);
}

// ---------------------------------------------------------------------------
// Kernel 1: gather + transpose + bf16-encode weights. (unchanged, KPAD=2496)
// ---------------------------------------------------------------------------
__global__ __launch_bounds__(256) void build_w(
    const int* __restrict__ symm,
    const int* __restrict__ c0s, const int* __restrict__ c1s,
    const int* __restrict__ c2s, const int* __restrict__ c3s,
    const float* __restrict__ sk,
    const float* __restrict__ ck0, const float* __restrict__ ck1,
    const float* __restrict__ ck2, const float* __restrict__ ck3,
    const float* __restrict__ l0k, const float* __restrict__ l1k,
    ushort_t* __restrict__ Wb, ushort_t* __restrict__ LWb)
{
    __shared__ int idx[2352];
    const int s = blockIdx.x;
    const int tid = threadIdx.x;
    for (int i = tid; i < 1152; i += 256) idx[i] = symm[s * N_ + i];
    for (int i = tid; i < 576; i += 256) idx[1152 + i] = c0s[s * 576 + i];
    for (int i = tid; i < 576; i += 256) idx[1728 + i] = c1s[s * 576 + i];
    if (tid < 24) idx[2304 + tid] = c2s[s * 24 + tid];
    else if (tid < 48) idx[2328 + (tid - 24)] = c3s[s * 24 + (tid - 24)];
    __syncthreads();
    for (int f = 0; f < 8; ++f) {
        ushort_t* wr = Wb + (size_t)(s * 8 + f) * KPAD;
        for (int k = tid; k < KPAD; k += 256) {
            ushort_t o;
            if (k < 1152)      o = bf16_rne(sk[f * N_ + idx[k]]);
            else if (k < 1728) o = bf16_rne(ck0[f * 576 + idx[k]]);
            else if (k < 2304) o = bf16_rne(ck1[f * 576 + idx[k]]);
            else if (k < 2448) {
                int q = k - 2304, g = q / 48, c = q - g * 48;
                float w = (c < 24) ? ck2[f * 24 + idx[2304 + c]]
                                   : ck3[f * 24 + idx[2328 + (c - 24)]];
                ushort_t hi = bf16_rne(w);
                o = (g < 2) ? hi : bf16_rne(w - bf16_to_f(hi));
            } else o = 0;
            wr[k] = o;
        }
        ushort_t* lr = LWb + (size_t)(s * 8 + f) * KLOOP;
        for (int k2 = tid; k2 < KLOOP; k2 += 256) {
            int j2 = k2 >> 7, q = k2 & 127;
            ushort_t o = 0;
            if (q < 72) {
                int g = q / 24, c = q - g * 24;
                float w = j2 ? l1k[f * 24 + idx[2328 + c]]
                             : l0k[f * 24 + idx[2304 + c]];
                ushort_t hi = bf16_rne(w);
                o = (g < 2) ? hi : bf16_rne(w - bf16_to_f(hi));
            }
            lr[k2] = o;
        }
    }
}

// ---------------------------------------------------------------------------
// Kernel 2: augmented A matrix (bf16) + loop-cv matrix + scalar bias.
// ---------------------------------------------------------------------------
__global__ __launch_bounds__(256) void build_cv(
    const float* __restrict__ x,
    const int* __restrict__ corr0, const int* __restrict__ corr1,
    const int* __restrict__ corr2, const int* __restrict__ corr3,
    const float* __restrict__ vb,
    const float* __restrict__ cb0, const float* __restrict__ cb1,
    const float* __restrict__ cb2, const float* __restrict__ cb3,
    ushort_t* __restrict__ XA, ushort_t* __restrict__ CVL,
    float* __restrict__ initb)
{
    __shared__ float xs[N_];
    __shared__ float red[256];
    __shared__ float cvhi[48], cvlo[48];
    const int tid = threadIdx.x;
    const int b = blockIdx.x;
    ushort_t* xr = XA + (size_t)b * KPAD;

    float bias = 0.f;
    const float vb0 = vb[0], vb1 = vb[1];
    for (int i = tid; i < N_; i += 256) {
        float v = x[(size_t)b * N_ + i];
        xs[i] = v;
        bias += v * ((i & 1) ? vb1 : vb0);
        xr[i] = bf16_rne(v);
    }
    __syncthreads();
    float s0 = 0.f, s1 = 0.f, s2 = 0.f, s3 = 0.f;
    for (int c = tid; c < 576; c += 256) {
        const int* i0 = corr0 + c * 4;
        float p = xs[i0[0]] * xs[i0[1]] * xs[i0[2]] * xs[i0[3]];
        xr[1152 + c] = bf16_rne(p); s0 += p;
        const int* i1 = corr1 + c * 4;
        float q = xs[i1[0]] * xs[i1[1]] * xs[i1[2]] * xs[i1[3]];
        xr[1728 + c] = bf16_rne(q); s1 += q;
    }
    if (tid < 48) {
        int j2 = tid / 24, c = tid - j2 * 24;
        const int* ii = (j2 ? corr3 : corr2) + c * 24;
        float p = 1.f;
        for (int j = 0; j < 24; ++j) p *= xs[ii[j]];
        float hv = bf16_to_f(bf16_rne(p));
        cvhi[tid] = hv;
        cvlo[tid] = p - hv;
        if (j2) s3 = p; else s2 = p;
    }
    __syncthreads();
    for (int i = tid; i < KPAD - 2304; i += 256) {
        ushort_t o = 0;
        if (i < 144) {
            int g = i / 48, c = i - g * 48;
            o = bf16_rne(g == 1 ? cvlo[c] : cvhi[c]);
        }
        xr[2304 + i] = o;
    }
    ushort_t* cr = CVL + (size_t)b * KLOOP;
    for (int k2 = tid; k2 < KLOOP; k2 += 256) {
        int j2 = k2 >> 7, q = k2 & 127;
        ushort_t o = 0;
        if (q < 72) {
            int g = q / 24, c = q - g * 24;
            o = bf16_rne(g == 1 ? cvlo[j2 * 24 + c] : cvhi[j2 * 24 + c]);
        }
        cr[k2] = o;
    }
    bias += cb0[0] * s0 + cb1[0] * s1 + cb2[0] * s2 + cb3[0] * s3;
    red[tid] = bias;
    __syncthreads();
    for (int off = 128; off; off >>= 1) {
        if (tid < off) red[tid] += red[tid + off];
        __syncthreads();
    }
    if (tid == 0) initb[b] = red[0];
}

// ---------------------------------------------------------------------------
// Kernel 3: 256x256 MFMA GEMM, 8 waves (2M x 4N), BK=64, 8-phase schedule
// (m201 port). LDS: 2 tile-buffers x 4 chunks {Aks0,Bks0,Aks1,Bks1}, chunk =
// 256 rows x 32 k bf16 (16 KiB, 2 gloads/thread). Per tile, 4 phases:
//   ph(ks,mih): {ds_reads (8 or 4 b128) || stage 1 chunk of tile t+1
//     -> s_barrier -> lgkmcnt(0)+sched_barrier -> setprio(1) 16 MFMA
//     setprio(0) -> [vmcnt(4) at ph2/ph4] -> s_barrier}
// vmcnt(4) proof: at ph2, newer loads = t.ph1+t.ph2 (4) => tile-t ks1 chunks
// (issued t-1.ph3/ph4) complete before ph3 reads. At ph4, newer = t.ph3+t.ph4
// => tile-(t+1) ks0 chunks complete before t+1.ph1 reads. Never 0 in steady
// state. Swizzle: phys_granule = lg ^ ((row>>1)&3) both sides (round-5
// verified, 0 conflicts).
// ---------------------------------------------------------------------------
__global__ __launch_bounds__(512, 2) void mfma_gemm(
    const ushort_t* __restrict__ XA, const ushort_t* __restrict__ Wb,
    const ushort_t* __restrict__ CVL, const ushort_t* __restrict__ LWb,
    const float* __restrict__ hidden_bias,
    const float* __restrict__ l0hb, const float* __restrict__ l1hb,
    float* __restrict__ partials)
{
    __shared__ __align__(16) ushort_t sh[65536];  // 2 bufs x 4 chunks x 8192

    const int tid = threadIdx.x;
    const int l = tid & 63, w = tid >> 6;
    const int wm = w >> 2, wn = w & 3;            // 2 M-waves x 4 N-waves
    const int lrow = l & 15, lg = l >> 4;
    const int srow = l >> 2;
    const int sgr8 = ((l & 3) ^ ((srow >> 1) & 3)) * 8;  // stage src swizzle

    // bijective XCD swizzle: 1152 blocks = 8 chunks x 144
    const int bid = blockIdx.x;
    const int swz = (bid & 7) * 144 + (bid >> 3);
    const int nt = swz % NT2, bt = swz / NT2;
    const int n0 = nt * 256, b0 = bt * 256;

    const ushort_t* XAb  = XA  + (size_t)b0 * KPAD;
    const ushort_t* Wbb  = Wb  + (size_t)n0 * KPAD;
    const ushort_t* CVb  = CVL + (size_t)b0 * KLOOP;
    const ushort_t* LWbb = LWb + (size_t)n0 * KLOOP;

    floatx4 acc[8][4];
    short8 bfr[4];

    // stage one 256x32 chunk: 2 gloads/thread
    auto STG = [&](const ushort_t* g, int stride, int kg, int ldsOff) {
#pragma unroll
        for (int i = 0; i < 2; ++i) {
            const int r0 = i * 128 + w * 16;
            gload16(g + (size_t)(r0 + srow) * stride + kg + sgr8,
                    &sh[ldsOff + r0 * 32]);
        }
    };

    const int ga = (lg ^ ((lrow >> 1) & 3)) * 8;   // read-side swizzle
    const int abase = (wm * 128 + lrow) * 32 + ga;
    const int bbase = (wn * 64 + lrow) * 32 + ga;

    // one phase: asrc/bsrc = LDS chunk offsets; mih = mi-half; sg nullable
    auto PHASE = [&](int asrc, int bsrc, int mih,
                     const ushort_t* sg, int sstride, int skg, int sdst,
                     int vf) {
        short8 afb[4];
        if (mih == 0) {
#pragma unroll
            for (int ni = 0; ni < 4; ++ni)
                bfr[ni] = *(const short8*)&sh[bsrc + bbase + ni * 512];
        }
#pragma unroll
        for (int mi = 0; mi < 4; ++mi)
            afb[mi] = *(const short8*)&sh[asrc + abase + mih * 2048 + mi * 512];
        if (sg) STG(sg, sstride, skg, sdst);
        __builtin_amdgcn_sched_barrier(0);
        __builtin_amdgcn_s_barrier();
        asm volatile("s_waitcnt lgkmcnt(0)" ::: "memory");
        __builtin_amdgcn_sched_barrier(0);
        __builtin_amdgcn_s_setprio(1);
#pragma unroll
        for (int mi = 0; mi < 4; ++mi)
#pragma unroll
            for (int ni = 0; ni < 4; ++ni)
                acc[mih * 4 + mi][ni] = __builtin_amdgcn_mfma_f32_16x16x32_bf16(
                    afb[mi], bfr[ni], acc[mih * 4 + mi][ni], 0, 0, 0);
        __builtin_amdgcn_s_setprio(0);
        if (vf == 1) asm volatile("s_waitcnt vmcnt(4)" ::: "memory");
        else if (vf == 2) asm volatile("s_waitcnt vmcnt(0)" ::: "memory");
        __builtin_amdgcn_sched_barrier(0);
        __builtin_amdgcn_s_barrier();
    };

#pragma unroll
    for (int mi = 0; mi < 8; ++mi)
#pragma unroll
        for (int ni = 0; ni < 4; ++ni) acc[mi][ni] = (floatx4){0.f, 0.f, 0.f, 0.f};

    // ---- prologue: stage tile 0 (4 chunks), first 2 resident ----
    STG(XAb, KPAD, 0, 0);      STG(Wbb, KPAD, 0, 8192);
    STG(XAb, KPAD, 32, 16384); STG(Wbb, KPAD, 32, 24576);
    asm volatile("s_waitcnt vmcnt(4)" ::: "memory");
    __builtin_amdgcn_s_barrier();

    // ---- main loop: tiles 0..37 stage tile t+1; tile 38 peeled ----
#pragma unroll 1
    for (int t = 0; t < NKT - 1; ++t) {
        const int cb = (t & 1) * 32768, nb = cb ^ 32768;
        const int kg = (t + 1) * 64;
        PHASE(cb,         cb + 8192,  0, XAb, KPAD, kg,      nb,         0);
        PHASE(cb,         cb + 8192,  1, Wbb, KPAD, kg,      nb + 8192,  1);
        PHASE(cb + 16384, cb + 24576, 0, XAb, KPAD, kg + 32, nb + 16384, 0);
        PHASE(cb + 16384, cb + 24576, 1, Wbb, KPAD, kg + 32, nb + 24576, 1);
    }
    {   // tile 38 (even -> buf0), no staging; vmcnt(0) validates its ks1
        PHASE(0,     8192,  0, nullptr, 0, 0, 0, 0);
        PHASE(0,     8192,  1, nullptr, 0, 0, 0, 2);
        PHASE(16384, 24576, 0, nullptr, 0, 0, 0, 0);
        PHASE(16384, 24576, 1, nullptr, 0, 0, 0, 0);
    }

    // ---- main log_cosh rowsums (D: row=lg*4+reg within frag, col=lrow) ----
    float rs[32];
    {
        const float hbv = hidden_bias[l & 7];
#pragma unroll
        for (int mi = 0; mi < 8; ++mi)
#pragma unroll
            for (int reg = 0; reg < 4; ++reg) {
                float t = 0.f;
#pragma unroll
                for (int ni = 0; ni < 4; ++ni)
                    t += log_cosh_f(acc[mi][ni][reg] + hbv);
                rs[mi * 4 + reg] = t;
            }
    }

    // ---- loop-correlator mini-GEMMs (2 K-tiles of 64 per j2), drain style --
#pragma unroll 1
    for (int j2 = 0; j2 < 2; ++j2) {
#pragma unroll
        for (int mi = 0; mi < 8; ++mi)
#pragma unroll
            for (int ni = 0; ni < 4; ++ni) acc[mi][ni] = (floatx4){0.f, 0.f, 0.f, 0.f};
        __syncthreads();
        const int kb = j2 * 128;
        STG(CVb, KLOOP, kb,      0);      STG(LWbb, KLOOP, kb,      8192);
        STG(CVb, KLOOP, kb + 32, 16384);  STG(LWbb, KLOOP, kb + 32, 24576);
        STG(CVb, KLOOP, kb + 64, 32768);  STG(LWbb, KLOOP, kb + 64, 40960);
        STG(CVb, KLOOP, kb + 96, 49152);  STG(LWbb, KLOOP, kb + 96, 57344);
        __syncthreads();   // drains vmcnt(0): all chunks resident
        PHASE(0,     8192,  0, nullptr, 0, 0, 0, 0);
        PHASE(0,     8192,  1, nullptr, 0, 0, 0, 0);
        PHASE(16384, 24576, 0, nullptr, 0, 0, 0, 0);
        PHASE(16384, 24576, 1, nullptr, 0, 0, 0, 0);
        PHASE(32768, 40960, 0, nullptr, 0, 0, 0, 0);
        PHASE(32768, 40960, 1, nullptr, 0, 0, 0, 0);
        PHASE(49152, 57344, 0, nullptr, 0, 0, 0, 0);
        PHASE(49152, 57344, 1, nullptr, 0, 0, 0, 0);
        const float lbv = (j2 ? l1hb : l0hb)[l & 7];
#pragma unroll
        for (int mi = 0; mi < 8; ++mi)
#pragma unroll
            for (int reg = 0; reg < 4; ++reg) {
                float t = 0.f;
#pragma unroll
                for (int ni = 0; ni < 4; ++ni)
                    t += log_cosh_f(acc[mi][ni][reg] + lbv);
                rs[mi * 4 + reg] += t;
            }
    }

    // ---- reduction: 16-lane shuffle then LDS red[256][5] ----
    __syncthreads();
    float* red = (float*)sh;
#pragma unroll
    for (int mi = 0; mi < 8; ++mi)
#pragma unroll
        for (int reg = 0; reg < 4; ++reg) {
            float v = rs[mi * 4 + reg];
            v += __shfl_xor(v, 1);
            v += __shfl_xor(v, 2);
            v += __shfl_xor(v, 4);
            v += __shfl_xor(v, 8);
            if (lrow == 0)
                red[(wm * 128 + mi * 16 + lg * 4 + reg) * 5 + wn] = v;
        }
    __syncthreads();
    if (tid < 256) {
        float t = red[tid * 5 + 0] + red[tid * 5 + 1] +
                  red[tid * 5 + 2] + red[tid * 5 + 3];
        partials[(size_t)nt * B_ + b0 + tid] = t;
    }
}

// ---------------------------------------------------------------------------
// Kernel 4: out[b] = initb[b] + sum over n-tiles
// ---------------------------------------------------------------------------
__global__ __launch_bounds__(256) void finalize_out(
    const float* __restrict__ initb, const float* __restrict__ partials,
    float* __restrict__ out)
{
    int b = blockIdx.x * 256 + threadIdx.x;
    float s = initb[b];
#pragma unroll
    for (int t = 0; t < NT2; ++t) s += partials[(size_t)t * B_ + b];
    out[b] = s;
}

extern "C" void kernel_launch(void* const* d_in, const int* in_sizes, int n_in,
                              void* d_out, int out_size, void* d_ws, size_t ws_size,
                              hipStream_t stream) {
    const float* x    = (const float*)d_in[0];
    const int* symm   = (const int*)d_in[1];
    const int* corr0  = (const int*)d_in[2];
    const int* corr1  = (const int*)d_in[3];
    const int* corr2  = (const int*)d_in[4];
    const int* corr3  = (const int*)d_in[5];
    const int* c0s    = (const int*)d_in[6];
    const int* c1s    = (const int*)d_in[7];
    const int* c2s    = (const int*)d_in[8];
    const int* c3s    = (const int*)d_in[9];
    const float* hb   = (const float*)d_in[10];
    const float* sk   = (const float*)d_in[11];
    const float* vb   = (const float*)d_in[12];
    const float* cb0  = (const float*)d_in[13];
    const float* ck0  = (const float*)d_in[14];
    const float* cb1  = (const float*)d_in[15];
    const float* ck1  = (const float*)d_in[16];
    const float* cb2  = (const float*)d_in[17];
    const float* ck2  = (const float*)d_in[18];
    const float* cb3  = (const float*)d_in[19];
    const float* ck3  = (const float*)d_in[20];
    const float* l0hb = (const float*)d_in[21];
    const float* l0k  = (const float*)d_in[22];
    const float* l1hb = (const float*)d_in[23];
    const float* l1k  = (const float*)d_in[24];

    ushort_t* wsu = (ushort_t*)d_ws;
    ushort_t* Wb  = wsu;                            // 4608*2496
    ushort_t* XA  = Wb + (size_t)NOUT * KPAD;       // 16384*2496
    ushort_t* LWb = XA + (size_t)B_ * KPAD;         // 4608*256
    ushort_t* CVL = LWb + (size_t)NOUT * KLOOP;     // 16384*256
    float* initb    = (float*)(CVL + (size_t)B_ * KLOOP);  // 16384
    float* partials = initb + B_;                          // 18*16384

    build_w<<<576, 256, 0, stream>>>(
        symm, c0s, c1s, c2s, c3s, sk, ck0, ck1, ck2, ck3, l0k, l1k, Wb, LWb);
    build_cv<<<B_, 256, 0, stream>>>(
        x, corr0, corr1, corr2, corr3, vb, cb0, cb1, cb2, cb3, XA, CVL, initb);
    mfma_gemm<<<1152, 512, 0, stream>>>(
        XA, Wb, CVL, LWb, hb, l0hb, l1hb, partials);
    finalize_out<<<B_ / 256, 256, 0, stream>>>(initb, partials, (float*)d_out);
}

// Round 7
// 579.471 us; speedup vs baseline: 7.6418x; 1.0542x over previous
//
#include <hip/hip_runtime.h>
#include <math.h>

#define B_    16384
#define N_    1152
#define KPAD  2496   // 1152 + 576 + 576 + 144 (cv23 3-slot) + 48 pad -> 78 x 32
#define NKT32 78     // K-tiles of 32
#define KLOOP 256    // per-j2: 72 slots + 56 pad -> 128, x2
#define NOUT  4608
#define NT2   18     // NOUT/256
#define LOG2F_ 0.69314718055994530942f

typedef unsigned short ushort_t;
typedef __attribute__((ext_vector_type(8))) short short8;
typedef __attribute__((ext_vector_type(4))) float floatx4;

__device__ __forceinline__ float log_cosh_f(float t) {
    float a = fabsf(t);
    return a + __logf(1.0f + __expf(-2.0f * a)) - LOG2F_;
}
__device__ __forceinline__ ushort_t bf16_rne(float f) {
    unsigned int u = __float_as_uint(f);
    return (ushort_t)((u + 0x7fffu + ((u >> 16) & 1u)) >> 16);
}
__device__ __forceinline__ float bf16_to_f(ushort_t h) {
    return __uint_as_float(((unsigned int)h) << 16);
}

typedef __attribute__((address_space(1))) const unsigned int guint;
typedef __attribute__((address_space(3))) unsigned int luint;
__device__ __forceinline__ void gload16(const ushort_t* src, ushort_t* dst) {
    __builtin_amdgcn_global_load_lds((guint*)src, (luint*)dst, 16, 0, 0);
}

// ---------------------------------------------------------------------------
// Kernel 1: gather + transpose + bf16-encode weights. (unchanged)
// ---------------------------------------------------------------------------
__global__ __launch_bounds__(256) void build_w(
    const int* __restrict__ symm,
    const int* __restrict__ c0s, const int* __restrict__ c1s,
    const int* __restrict__ c2s, const int* __restrict__ c3s,
    const float* __restrict__ sk,
    const float* __restrict__ ck0, const float* __restrict__ ck1,
    const float* __restrict__ ck2, const float* __restrict__ ck3,
    const float* __restrict__ l0k, const float* __restrict__ l1k,
    ushort_t* __restrict__ Wb, ushort_t* __restrict__ LWb)
{
    __shared__ int idx[2352];
    const int s = blockIdx.x;
    const int tid = threadIdx.x;
    for (int i = tid; i < 1152; i += 256) idx[i] = symm[s * N_ + i];
    for (int i = tid; i < 576; i += 256) idx[1152 + i] = c0s[s * 576 + i];
    for (int i = tid; i < 576; i += 256) idx[1728 + i] = c1s[s * 576 + i];
    if (tid < 24) idx[2304 + tid] = c2s[s * 24 + tid];
    else if (tid < 48) idx[2328 + (tid - 24)] = c3s[s * 24 + (tid - 24)];
    __syncthreads();
    for (int f = 0; f < 8; ++f) {
        ushort_t* wr = Wb + (size_t)(s * 8 + f) * KPAD;
        for (int k = tid; k < KPAD; k += 256) {
            ushort_t o;
            if (k < 1152)      o = bf16_rne(sk[f * N_ + idx[k]]);
            else if (k < 1728) o = bf16_rne(ck0[f * 576 + idx[k]]);
            else if (k < 2304) o = bf16_rne(ck1[f * 576 + idx[k]]);
            else if (k < 2448) {
                int q = k - 2304, g = q / 48, c = q - g * 48;
                float w = (c < 24) ? ck2[f * 24 + idx[2304 + c]]
                                   : ck3[f * 24 + idx[2328 + (c - 24)]];
                ushort_t hi = bf16_rne(w);
                o = (g < 2) ? hi : bf16_rne(w - bf16_to_f(hi));
            } else o = 0;
            wr[k] = o;
        }
        ushort_t* lr = LWb + (size_t)(s * 8 + f) * KLOOP;
        for (int k2 = tid; k2 < KLOOP; k2 += 256) {
            int j2 = k2 >> 7, q = k2 & 127;
            ushort_t o = 0;
            if (q < 72) {
                int g = q / 24, c = q - g * 24;
                float w = j2 ? l1k[f * 24 + idx[2328 + c]]
                             : l0k[f * 24 + idx[2304 + c]];
                ushort_t hi = bf16_rne(w);
                o = (g < 2) ? hi : bf16_rne(w - bf16_to_f(hi));
            }
            lr[k2] = o;
        }
    }
}

// ---------------------------------------------------------------------------
// Kernel 2: augmented A matrix (bf16) + loop-cv matrix + scalar bias. (same)
// ---------------------------------------------------------------------------
__global__ __launch_bounds__(256) void build_cv(
    const float* __restrict__ x,
    const int* __restrict__ corr0, const int* __restrict__ corr1,
    const int* __restrict__ corr2, const int* __restrict__ corr3,
    const float* __restrict__ vb,
    const float* __restrict__ cb0, const float* __restrict__ cb1,
    const float* __restrict__ cb2, const float* __restrict__ cb3,
    ushort_t* __restrict__ XA, ushort_t* __restrict__ CVL,
    float* __restrict__ initb)
{
    __shared__ float xs[N_];
    __shared__ float red[256];
    __shared__ float cvhi[48], cvlo[48];
    const int tid = threadIdx.x;
    const int b = blockIdx.x;
    ushort_t* xr = XA + (size_t)b * KPAD;

    float bias = 0.f;
    const float vb0 = vb[0], vb1 = vb[1];
    for (int i = tid; i < N_; i += 256) {
        float v = x[(size_t)b * N_ + i];
        xs[i] = v;
        bias += v * ((i & 1) ? vb1 : vb0);
        xr[i] = bf16_rne(v);
    }
    __syncthreads();
    float s0 = 0.f, s1 = 0.f, s2 = 0.f, s3 = 0.f;
    for (int c = tid; c < 576; c += 256) {
        const int* i0 = corr0 + c * 4;
        float p = xs[i0[0]] * xs[i0[1]] * xs[i0[2]] * xs[i0[3]];
        xr[1152 + c] = bf16_rne(p); s0 += p;
        const int* i1 = corr1 + c * 4;
        float q = xs[i1[0]] * xs[i1[1]] * xs[i1[2]] * xs[i1[3]];
        xr[1728 + c] = bf16_rne(q); s1 += q;
    }
    if (tid < 48) {
        int j2 = tid / 24, c = tid - j2 * 24;
        const int* ii = (j2 ? corr3 : corr2) + c * 24;
        float p = 1.f;
        for (int j = 0; j < 24; ++j) p *= xs[ii[j]];
        float hv = bf16_to_f(bf16_rne(p));
        cvhi[tid] = hv;
        cvlo[tid] = p - hv;
        if (j2) s3 = p; else s2 = p;
    }
    __syncthreads();
    for (int i = tid; i < KPAD - 2304; i += 256) {
        ushort_t o = 0;
        if (i < 144) {
            int g = i / 48, c = i - g * 48;
            o = bf16_rne(g == 1 ? cvlo[c] : cvhi[c]);
        }
        xr[2304 + i] = o;
    }
    ushort_t* cr = CVL + (size_t)b * KLOOP;
    for (int k2 = tid; k2 < KLOOP; k2 += 256) {
        int j2 = k2 >> 7, q = k2 & 127;
        ushort_t o = 0;
        if (q < 72) {
            int g = q / 24, c = q - g * 24;
            o = bf16_rne(g == 1 ? cvlo[j2 * 24 + c] : cvhi[j2 * 24 + c]);
        }
        cr[k2] = o;
    }
    bias += cb0[0] * s0 + cb1[0] * s1 + cb2[0] * s2 + cb3[0] * s3;
    red[tid] = bias;
    __syncthreads();
    for (int off = 128; off; off >>= 1) {
        if (tid < off) red[tid] += red[tid + off];
        __syncthreads();
    }
    if (tid == 0) initb[b] = red[0];
}

// ---------------------------------------------------------------------------
// Kernel 3: 128x256-tile MFMA GEMM, 8 waves (2M x 4N), per-wave 64x64
// (acc=64 regs), BK=32, THREE 24KB LDS buffers (72KB) -> with
// __launch_bounds__(512,4) gives 2 blocks/CU: independent blocks fill each
// other's barrier/read gaps (the round-4..6 schedules were section-serialized
// at 1 block/CU). Depth-2 prefetch, counted vmcnt(3), 1 barrier/tile,
// stage-after-barrier (prev-buffer reads provably consumed).
// Swizzle: phys_granule = lg ^ ((row>>1)&3), both sides (verified 0-conflict).
// ---------------------------------------------------------------------------
__global__ __launch_bounds__(512, 4) void mfma_gemm(
    const ushort_t* __restrict__ XA, const ushort_t* __restrict__ Wb,
    const ushort_t* __restrict__ CVL, const ushort_t* __restrict__ LWb,
    const float* __restrict__ hidden_bias,
    const float* __restrict__ l0hb, const float* __restrict__ l1hb,
    float* __restrict__ partials)
{
    // 3 buffers x (A 128x32 = 4096 us | B 256x32 = 8192 us) = 36864 ushorts
    __shared__ __align__(16) ushort_t sh[36864];
    __shared__ float redsh[640];   // [128 rows][5] rowsum accumulators

    const int tid = threadIdx.x;
    const int l = tid & 63, w = tid >> 6;
    const int wm = w >> 2, wn = w & 3;           // 2 M-waves x 4 N-waves
    const int lrow = l & 15, lg = l >> 4;
    const int srow = l >> 2;
    const int sgr8 = ((l & 3) ^ ((srow >> 1) & 3)) * 8;  // stage src swizzle

    // bijective XCD swizzle, bt-fastest: Wb column tile (1.25MB) stays L2-hot
    const int bid = blockIdx.x;                  // grid 2304 = 8 x 288
    const int swz = (bid & 7) * 288 + (bid >> 3);
    const int nt = swz >> 7, bt = swz & 127;     // nt = swz/128 (0..17)
    const int n0 = nt * 256, b0 = bt * 128;

    const ushort_t* XAb  = XA  + (size_t)b0 * KPAD;
    const ushort_t* Wbb  = Wb  + (size_t)n0 * KPAD;
    const ushort_t* CVb  = CVL + (size_t)b0 * KLOOP;
    const ushort_t* LWbb = LWb + (size_t)n0 * KLOOP;

    floatx4 acc[4][4];

    // stage A chunk (128 rows x 32 k): 1 gload/thread
    auto STGA = [&](const ushort_t* g, int stride, int kg, int bo) {
        gload16(g + (size_t)(w * 16 + srow) * stride + kg + sgr8,
                &sh[bo + w * 16 * 32]);
    };
    // stage B chunk (256 rows x 32 k): 2 gloads/thread
    auto STGB = [&](const ushort_t* g, int stride, int kg, int bo) {
#pragma unroll
        for (int i = 0; i < 2; ++i) {
            const int r0 = i * 128 + w * 16;
            gload16(g + (size_t)(r0 + srow) * stride + kg + sgr8,
                    &sh[bo + 4096 + r0 * 32]);
        }
    };

    const int ga = (lg ^ ((lrow >> 1) & 3)) * 8;   // read-side swizzle
    const int abase = (wm * 64 + lrow) * 32 + ga;
    const int bbase = 4096 + (wn * 64 + lrow) * 32 + ga;

    // one BK=32 tile: 8 ds_read_b128 + 16 MFMA (compiler manages lgkmcnt)
    auto TILE = [&](int bo) {
        short8 af[4], bfr[4];
#pragma unroll
        for (int mi = 0; mi < 4; ++mi)
            af[mi] = *(const short8*)&sh[bo + abase + mi * 512];
#pragma unroll
        for (int ni = 0; ni < 4; ++ni)
            bfr[ni] = *(const short8*)&sh[bo + bbase + ni * 512];
        __builtin_amdgcn_s_setprio(1);
#pragma unroll
        for (int mi = 0; mi < 4; ++mi)
#pragma unroll
            for (int ni = 0; ni < 4; ++ni)
                acc[mi][ni] = __builtin_amdgcn_mfma_f32_16x16x32_bf16(
                    af[mi], bfr[ni], acc[mi][ni], 0, 0, 0);
        __builtin_amdgcn_s_setprio(0);
    };

#pragma unroll
    for (int mi = 0; mi < 4; ++mi)
#pragma unroll
        for (int ni = 0; ni < 4; ++ni) acc[mi][ni] = (floatx4){0.f, 0.f, 0.f, 0.f};

    // ---- main K loop: 78 tiles, 3 buffers, depth-2 prefetch ----
    int c0 = 0, c1 = 12288, c2 = 24576;
    STGA(XAb, KPAD, 0, c0);  STGB(Wbb, KPAD, 0, c0);
    STGA(XAb, KPAD, 32, c1); STGB(Wbb, KPAD, 32, c1);
#pragma unroll 1
    for (int t = 0; t < NKT32 - 1; ++t) {
        asm volatile("s_waitcnt vmcnt(3)" ::: "memory");
        __builtin_amdgcn_s_barrier();
        if (t < NKT32 - 2) {
            STGA(XAb, KPAD, (t + 2) * 32, c2);
            STGB(Wbb, KPAD, (t + 2) * 32, c2);
        }
        TILE(c0);
        int tmp = c0; c0 = c1; c1 = c2; c2 = tmp;
    }
    asm volatile("s_waitcnt vmcnt(0)" ::: "memory");
    __builtin_amdgcn_s_barrier();
    TILE(c0);

    // ---- main log_cosh rowsums -> redsh (frees registers for mini-GEMM) ----
    // D layout: row = lg*4+reg within 16-frag, col = lrow; f = lrow&7 = l&7
    {
        const float hbv = hidden_bias[l & 7];
#pragma unroll
        for (int mi = 0; mi < 4; ++mi)
#pragma unroll
            for (int reg = 0; reg < 4; ++reg) {
                float v = 0.f;
#pragma unroll
                for (int ni = 0; ni < 4; ++ni)
                    v += log_cosh_f(acc[mi][ni][reg] + hbv);
                v += __shfl_xor(v, 1);
                v += __shfl_xor(v, 2);
                v += __shfl_xor(v, 4);
                v += __shfl_xor(v, 8);
                if (lrow == 0)
                    redsh[(wm * 64 + mi * 16 + lg * 4 + reg) * 5 + wn] = v;
            }
    }

    // ---- loop-correlator mini-GEMMs (K=128 per j2), same 3-buf pipeline ----
#pragma unroll 1
    for (int j2 = 0; j2 < 2; ++j2) {
#pragma unroll
        for (int mi = 0; mi < 4; ++mi)
#pragma unroll
            for (int ni = 0; ni < 4; ++ni) acc[mi][ni] = (floatx4){0.f, 0.f, 0.f, 0.f};
        __syncthreads();   // all waves done with previous buffer contents
        const int kb = j2 * 128;
        STGA(CVb, KLOOP, kb, 0);          STGB(LWbb, KLOOP, kb, 0);
        STGA(CVb, KLOOP, kb + 32, 12288); STGB(LWbb, KLOOP, kb + 32, 12288);
        int m0 = 0, m1 = 12288, m2 = 24576;
#pragma unroll 1
        for (int t = 0; t < 4; ++t) {
            if (t < 3) asm volatile("s_waitcnt vmcnt(3)" ::: "memory");
            else       asm volatile("s_waitcnt vmcnt(0)" ::: "memory");
            __builtin_amdgcn_s_barrier();
            if (t < 2) {
                STGA(CVb, KLOOP, kb + (t + 2) * 32, m2);
                STGB(LWbb, KLOOP, kb + (t + 2) * 32, m2);
            }
            TILE(m0);
            int tmp = m0; m0 = m1; m1 = m2; m2 = tmp;
        }
        const float lbv = (j2 ? l1hb : l0hb)[l & 7];
#pragma unroll
        for (int mi = 0; mi < 4; ++mi)
#pragma unroll
            for (int reg = 0; reg < 4; ++reg) {
                float v = 0.f;
#pragma unroll
                for (int ni = 0; ni < 4; ++ni)
                    v += log_cosh_f(acc[mi][ni][reg] + lbv);
                v += __shfl_xor(v, 1);
                v += __shfl_xor(v, 2);
                v += __shfl_xor(v, 4);
                v += __shfl_xor(v, 8);
                if (lrow == 0)
                    redsh[(wm * 64 + mi * 16 + lg * 4 + reg) * 5 + wn] += v;
            }
    }

    // ---- final cross-wave sum ----
    __syncthreads();
    if (tid < 128) {
        float t = redsh[tid * 5 + 0] + redsh[tid * 5 + 1] +
                  redsh[tid * 5 + 2] + redsh[tid * 5 + 3];
        partials[(size_t)nt * B_ + b0 + tid] = t;
    }
}

// ---------------------------------------------------------------------------
// Kernel 4: out[b] = initb[b] + sum over n-tiles
// ---------------------------------------------------------------------------
__global__ __launch_bounds__(256) void finalize_out(
    const float* __restrict__ initb, const float* __restrict__ partials,
    float* __restrict__ out)
{
    int b = blockIdx.x * 256 + threadIdx.x;
    float s = initb[b];
#pragma unroll
    for (int t = 0; t < NT2; ++t) s += partials[(size_t)t * B_ + b];
    out[b] = s;
}

extern "C" void kernel_launch(void* const* d_in, const int* in_sizes, int n_in,
                              void* d_out, int out_size, void* d_ws, size_t ws_size,
                              hipStream_t stream) {
    const float* x    = (const float*)d_in[0];
    const int* symm   = (const int*)d_in[1];
    const int* corr0  = (const int*)d_in[2];
    const int* corr1  = (const int*)d_in[3];
    const int* corr2  = (const int*)d_in[4];
    const int* corr3  = (const int*)d_in[5];
    const int* c0s    = (const int*)d_in[6];
    const int* c1s    = (const int*)d_in[7];
    const int* c2s    = (const int*)d_in[8];
    const int* c3s    = (const int*)d_in[9];
    const float* hb   = (const float*)d_in[10];
    const float* sk   = (const float*)d_in[11];
    const float* vb   = (const float*)d_in[12];
    const float* cb0  = (const float*)d_in[13];
    const float* ck0  = (const float*)d_in[14];
    const float* cb1  = (const float*)d_in[15];
    const float* ck1  = (const float*)d_in[16];
    const float* cb2  = (const float*)d_in[17];
    const float* ck2  = (const float*)d_in[18];
    const float* cb3  = (const float*)d_in[19];
    const float* ck3  = (const float*)d_in[20];
    const float* l0hb = (const float*)d_in[21];
    const float* l0k  = (const float*)d_in[22];
    const float* l1hb = (const float*)d_in[23];
    const float* l1k  = (const float*)d_in[24];

    ushort_t* wsu = (ushort_t*)d_ws;
    ushort_t* Wb  = wsu;                            // 4608*2496
    ushort_t* XA  = Wb + (size_t)NOUT * KPAD;       // 16384*2496
    ushort_t* LWb = XA + (size_t)B_ * KPAD;         // 4608*256
    ushort_t* CVL = LWb + (size_t)NOUT * KLOOP;     // 16384*256
    float* initb    = (float*)(CVL + (size_t)B_ * KLOOP);  // 16384
    float* partials = initb + B_;                          // 18*16384

    build_w<<<576, 256, 0, stream>>>(
        symm, c0s, c1s, c2s, c3s, sk, ck0, ck1, ck2, ck3, l0k, l1k, Wb, LWb);
    build_cv<<<B_, 256, 0, stream>>>(
        x, corr0, corr1, corr2, corr3, vb, cb0, cb1, cb2, cb3, XA, CVL, initb);
    mfma_gemm<<<2304, 512, 0, stream>>>(
        XA, Wb, CVL, LWb, hb, l0hb, l1hb, partials);
    finalize_out<<<B_ / 256, 256, 0, stream>>>(initb, partials, (float*)d_out);
}